// Round 2
// baseline (730.728 us; speedup 1.0000x reference)
//
#include <hip/hip_runtime.h>

#define N_NODES 50000

// Workspace layout (float offsets):
//   dinv : [0, 50000)
//   h1   : [51200, +6400000)          50000x128
//   out1 : [6451200, +6400000)        50000x128
//   h2   : [12851200, +3200000)       50000x64
//   out2 : [16051200, +3200000)       50000x64
// total = 19,251,200 floats = 77.0 MB

__global__ __launch_bounds__(256) void k_init_deg(float* __restrict__ deg) {
  int i = blockIdx.x * 256 + threadIdx.x;
  if (i < N_NODES) deg[i] = 1.0f;  // self-loop contributes 1 to every node's degree
}

__global__ __launch_bounds__(256) void k_count_deg(const int* __restrict__ dst, int E,
                                                   float* __restrict__ deg) {
  int i = blockIdx.x * 256 + threadIdx.x;
  if (i < E) atomicAdd(&deg[dst[i]], 1.0f);
}

__global__ __launch_bounds__(256) void k_dinv(float* __restrict__ deg) {
  int i = blockIdx.x * 256 + threadIdx.x;
  if (i < N_NODES) deg[i] = rsqrtf(deg[i]);  // deg >= 1 always (self-loop)
}

// h1 = x @ W1 ; out1 = h1 * dinv^2 + b1   (self-loop term + bias pre-seeded)
// grid = (3125, 2): blockIdx.x = node group of 16, blockIdx.y = feature half (64 cols)
__global__ __launch_bounds__(256) void k_gemm1(const float* __restrict__ x,
                                               const float* __restrict__ W1,
                                               const float* __restrict__ b1,
                                               const float* __restrict__ dinv,
                                               float* __restrict__ h1,
                                               float* __restrict__ out1) {
  __shared__ float Wl[128 * 64];   // 32 KB: W1[:, fh*64 : fh*64+64]
  __shared__ float xs[16][128];    // 8 KB: 16 node rows
  const int fh = blockIdx.y;
  const int f  = threadIdx.x & 63;
  const int q  = threadIdx.x >> 6;           // wave id 0..3 -> node subgroup
  const int n0 = blockIdx.x * 16;

  for (int i = threadIdx.x; i < 128 * 64; i += 256) {
    int k = i >> 6, c = i & 63;
    Wl[i] = W1[k * 128 + fh * 64 + c];
  }
  for (int i = threadIdx.x; i < 16 * 128; i += 256) {
    int nn = i >> 7, kk = i & 127;
    xs[nn][kk] = x[(size_t)(n0 + nn) * 128 + kk];
  }
  __syncthreads();

  float acc[4] = {0.f, 0.f, 0.f, 0.f};
  for (int k = 0; k < 128; ++k) {
    float w = Wl[k * 64 + f];          // 64 lanes consecutive: 2 lanes/bank, free
    acc[0] += xs[q * 4 + 0][k] * w;    // wave-uniform addr: LDS broadcast
    acc[1] += xs[q * 4 + 1][k] * w;
    acc[2] += xs[q * 4 + 2][k] * w;
    acc[3] += xs[q * 4 + 3][k] * w;
  }
#pragma unroll
  for (int j = 0; j < 4; ++j) {
    int node = n0 + q * 4 + j;
    float dl = dinv[node];
    float v  = acc[j];
    h1[(size_t)node * 128 + fh * 64 + f]   = v;
    out1[(size_t)node * 128 + fh * 64 + f] = v * dl * dl + b1[fh * 64 + f];
  }
}

// out1[d] += h1[s] * dinv[s]*dinv[d]  -- one wave per edge, 128 feats = 2/lane
__global__ __launch_bounds__(256) void k_scatter1(const int* __restrict__ src,
                                                  const int* __restrict__ dst,
                                                  const float* __restrict__ dinv,
                                                  const float* __restrict__ h1,
                                                  float* __restrict__ out1, int E) {
  const int lane = threadIdx.x & 63;
  int w = blockIdx.x * 4 + (threadIdx.x >> 6);
  const int nw = gridDim.x * 4;
  for (int e = w; e < E; e += nw) {
    int s = src[e], d = dst[e];
    float nrm = dinv[s] * dinv[d];
    const float* hs = h1 + (size_t)s * 128;
    float* od = out1 + (size_t)d * 128;
    atomicAdd(&od[lane],      hs[lane]      * nrm);
    atomicAdd(&od[lane + 64], hs[lane + 64] * nrm);
  }
}

// h2 = relu(out1) @ W2 ; out2 = h2 * dinv^2 + b2
__global__ __launch_bounds__(256) void k_gemm2(const float* __restrict__ out1,
                                               const float* __restrict__ W2,
                                               const float* __restrict__ b2,
                                               const float* __restrict__ dinv,
                                               float* __restrict__ h2,
                                               float* __restrict__ out2) {
  __shared__ float Wl[128 * 64];   // 32 KB: full W2
  __shared__ float xs[16][128];    // 8 KB
  const int f = threadIdx.x & 63;
  const int q = threadIdx.x >> 6;
  const int n0 = blockIdx.x * 16;

  for (int i = threadIdx.x; i < 128 * 64; i += 256) Wl[i] = W2[i];
  for (int i = threadIdx.x; i < 16 * 128; i += 256) {
    int nn = i >> 7, kk = i & 127;
    xs[nn][kk] = fmaxf(out1[(size_t)(n0 + nn) * 128 + kk], 0.f);  // fused ReLU
  }
  __syncthreads();

  float acc[4] = {0.f, 0.f, 0.f, 0.f};
  for (int k = 0; k < 128; ++k) {
    float w = Wl[k * 64 + f];
    acc[0] += xs[q * 4 + 0][k] * w;
    acc[1] += xs[q * 4 + 1][k] * w;
    acc[2] += xs[q * 4 + 2][k] * w;
    acc[3] += xs[q * 4 + 3][k] * w;
  }
#pragma unroll
  for (int j = 0; j < 4; ++j) {
    int node = n0 + q * 4 + j;
    float dl = dinv[node];
    float v  = acc[j];
    h2[(size_t)node * 64 + f]   = v;
    out2[(size_t)node * 64 + f] = v * dl * dl + b2[f];
  }
}

// out2[d] += h2[s] * nrm  -- one wave per edge, 64 feats = 1/lane
__global__ __launch_bounds__(256) void k_scatter2(const int* __restrict__ src,
                                                  const int* __restrict__ dst,
                                                  const float* __restrict__ dinv,
                                                  const float* __restrict__ h2,
                                                  float* __restrict__ out2, int E) {
  const int lane = threadIdx.x & 63;
  int w = blockIdx.x * 4 + (threadIdx.x >> 6);
  const int nw = gridDim.x * 4;
  for (int e = w; e < E; e += nw) {
    int s = src[e], d = dst[e];
    float nrm = dinv[s] * dinv[d];
    atomicAdd(&out2[(size_t)d * 64 + lane], h2[(size_t)s * 64 + lane] * nrm);
  }
}

// logits[e] = dot(z[a[e]], z[b[e]])  over 64 dims -- one wave per edge
__global__ __launch_bounds__(256) void k_decode(const int* __restrict__ ia,
                                                const int* __restrict__ ib,
                                                const float* __restrict__ z,
                                                float* __restrict__ out, int M) {
  const int lane = threadIdx.x & 63;
  int w = blockIdx.x * 4 + (threadIdx.x >> 6);
  const int nw = gridDim.x * 4;
  for (int e = w; e < M; e += nw) {
    float v = z[(size_t)ia[e] * 64 + lane] * z[(size_t)ib[e] * 64 + lane];
    v += __shfl_down(v, 32, 64);
    v += __shfl_down(v, 16, 64);
    v += __shfl_down(v, 8, 64);
    v += __shfl_down(v, 4, 64);
    v += __shfl_down(v, 2, 64);
    v += __shfl_down(v, 1, 64);
    if (lane == 0) out[e] = v;
  }
}

extern "C" void kernel_launch(void* const* d_in, const int* in_sizes, int n_in,
                              void* d_out, int out_size, void* d_ws, size_t ws_size,
                              hipStream_t stream) {
  const float* x   = (const float*)d_in[0];
  const int*   ei  = (const int*)d_in[1];
  const int*   eli = (const int*)d_in[2];
  const float* W1  = (const float*)d_in[3];
  const float* b1  = (const float*)d_in[4];
  const float* W2  = (const float*)d_in[5];
  const float* b2  = (const float*)d_in[6];
  float* outp = (float*)d_out;

  const int E = in_sizes[1] / 2;   // 800000
  const int M = in_sizes[2] / 2;   // 200000
  const int* src = ei;
  const int* dst = ei + E;
  const int* la  = eli;
  const int* lb  = eli + M;

  float* ws   = (float*)d_ws;
  float* dinv = ws;
  float* h1   = ws + 51200;
  float* out1 = h1 + 6400000;
  float* h2   = out1 + 6400000;
  float* out2 = h2 + 3200000;

  k_init_deg<<<(N_NODES + 255) / 256, 256, 0, stream>>>(dinv);
  k_count_deg<<<(E + 255) / 256, 256, 0, stream>>>(dst, E, dinv);
  k_dinv<<<(N_NODES + 255) / 256, 256, 0, stream>>>(dinv);

  dim3 g1(3125, 2);
  k_gemm1<<<g1, 256, 0, stream>>>(x, W1, b1, dinv, h1, out1);
  k_scatter1<<<4096, 256, 0, stream>>>(src, dst, dinv, h1, out1, E);
  k_gemm2<<<3125, 256, 0, stream>>>(out1, W2, b2, dinv, h2, out2);
  k_scatter2<<<4096, 256, 0, stream>>>(src, dst, dinv, h2, out2, E);
  k_decode<<<2048, 256, 0, stream>>>(la, lb, out2, outp, M);
}

// Round 3
// 381.716 us; speedup vs baseline: 1.9143x; 1.9143x over previous
//
#include <hip/hip_runtime.h>

#define N_NODES 50000
#define NB ((N_NODES + 255) / 256)   // 196 scan blocks

// Workspace layout (4-byte units):
//   dinv   [0,       50000)   float
//   rowptr [50048,  100049)   int   (50001 entries)
//   bsum   [100096, 100352)   int
//   boff   [100352, 100608)   int
//   cnt    [100608, 150608)   int   (histogram, then reused as fill cursor)
//   esrc   [150656, 950656)   int   (src node per CSR slot)
//   h1p    [950784, +6400000)  float (h1 * dinv[n], 50000x128)  -- later reused:
//            h2p  = h1p      (50000x64)
//            out2 = h1p+3.2M (50000x64)
//   out1   [7350784, +6400000) float (50000x128)
// total = 13,750,784 floats = 55.0 MB

#define OFF_ROWPTR 50048
#define OFF_BSUM   100096
#define OFF_BOFF   100352
#define OFF_CNT    100608
#define OFF_ESRC   150656
#define OFF_H1     950784
#define OFF_OUT1   7350784

__global__ __launch_bounds__(256) void k_zero(int* __restrict__ cnt) {
  int i = blockIdx.x * 256 + threadIdx.x;
  if (i < N_NODES) cnt[i] = 0;
}

__global__ __launch_bounds__(256) void k_hist(const int* __restrict__ dst, int E,
                                              int* __restrict__ cnt) {
  int i = blockIdx.x * 256 + threadIdx.x;
  if (i < E) atomicAdd(&cnt[dst[i]], 1);
}

// block-local exclusive scan of cnt -> rowptr, block totals -> bsum
__global__ __launch_bounds__(256) void k_scan1(const int* __restrict__ cnt,
                                               int* __restrict__ rowptr,
                                               int* __restrict__ bsum) {
  __shared__ int tmp[256];
  int i = blockIdx.x * 256 + threadIdx.x;
  int v = (i < N_NODES) ? cnt[i] : 0;
  tmp[threadIdx.x] = v;
  __syncthreads();
  for (int off = 1; off < 256; off <<= 1) {
    int t = (threadIdx.x >= off) ? tmp[threadIdx.x - off] : 0;
    __syncthreads();
    tmp[threadIdx.x] += t;
    __syncthreads();
  }
  if (i < N_NODES) rowptr[i] = tmp[threadIdx.x] - v;  // exclusive
  if (threadIdx.x == 255) bsum[blockIdx.x] = tmp[255];
}

// single block: exclusive scan of 196 block sums
__global__ __launch_bounds__(256) void k_scan2(const int* __restrict__ bsum,
                                               int* __restrict__ boff) {
  __shared__ int tmp[256];
  int v = (threadIdx.x < NB) ? bsum[threadIdx.x] : 0;
  tmp[threadIdx.x] = v;
  __syncthreads();
  for (int off = 1; off < 256; off <<= 1) {
    int t = (threadIdx.x >= off) ? tmp[threadIdx.x - off] : 0;
    __syncthreads();
    tmp[threadIdx.x] += t;
    __syncthreads();
  }
  if (threadIdx.x < NB) boff[threadIdx.x] = tmp[threadIdx.x] - v;
}

// finalize rowptr, compute dinv = rsqrt(1+indeg), re-zero cnt (-> fill cursor)
__global__ __launch_bounds__(256) void k_scan3(int* __restrict__ rowptr,
                                               int* __restrict__ cnt,
                                               float* __restrict__ dinv,
                                               const int* __restrict__ boff, int E) {
  int i = blockIdx.x * 256 + threadIdx.x;
  if (i < N_NODES) {
    rowptr[i] += boff[blockIdx.x];
    dinv[i] = rsqrtf(1.0f + (float)cnt[i]);
    cnt[i] = 0;
  }
  if (i == 0) rowptr[N_NODES] = E;
}

__global__ __launch_bounds__(256) void k_fill(const int* __restrict__ src,
                                              const int* __restrict__ dst, int E,
                                              const int* __restrict__ rowptr,
                                              int* __restrict__ cursor,
                                              int* __restrict__ esrc) {
  int e = blockIdx.x * 256 + threadIdx.x;
  if (e < E) {
    int d = dst[e];
    int pos = atomicAdd(&cursor[d], 1);
    esrc[rowptr[d] + pos] = src[e];
  }
}

// h1p = (x @ W1) * dinv[n] ; out1 = (x @ W1) * dinv^2 + b1  (self-loop + bias seed)
__global__ __launch_bounds__(256) void k_gemm1(const float* __restrict__ x,
                                               const float* __restrict__ W1,
                                               const float* __restrict__ b1,
                                               const float* __restrict__ dinv,
                                               float* __restrict__ h1p,
                                               float* __restrict__ out1) {
  __shared__ float Wl[128 * 64];
  __shared__ float xs[16][128];
  const int fh = blockIdx.y;
  const int f  = threadIdx.x & 63;
  const int q  = threadIdx.x >> 6;
  const int n0 = blockIdx.x * 16;

  for (int i = threadIdx.x; i < 128 * 64; i += 256) {
    int k = i >> 6, c = i & 63;
    Wl[i] = W1[k * 128 + fh * 64 + c];
  }
  for (int i = threadIdx.x; i < 16 * 128; i += 256) {
    int nn = i >> 7, kk = i & 127;
    xs[nn][kk] = x[(size_t)(n0 + nn) * 128 + kk];
  }
  __syncthreads();

  float acc[4] = {0.f, 0.f, 0.f, 0.f};
  for (int k = 0; k < 128; ++k) {
    float w = Wl[k * 64 + f];
    acc[0] += xs[q * 4 + 0][k] * w;
    acc[1] += xs[q * 4 + 1][k] * w;
    acc[2] += xs[q * 4 + 2][k] * w;
    acc[3] += xs[q * 4 + 3][k] * w;
  }
#pragma unroll
  for (int j = 0; j < 4; ++j) {
    int node = n0 + q * 4 + j;
    float dl = dinv[node];
    float vd = acc[j] * dl;
    h1p[(size_t)node * 128 + fh * 64 + f]  = vd;          // pre-scaled by dinv[src]
    out1[(size_t)node * 128 + fh * 64 + f] = vd * dl + b1[fh * 64 + f];
  }
}

// out1[n] += dinv[n] * sum_{s in in(n)} h1p[s]   -- one wave per node, 2 f/lane
__global__ __launch_bounds__(256) void k_pull1(const int* __restrict__ rowptr,
                                               const int* __restrict__ esrc,
                                               const float* __restrict__ dinv,
                                               const float* __restrict__ h1p,
                                               float* __restrict__ out1) {
  int w = (blockIdx.x * 256 + threadIdx.x) >> 6;
  int lane = threadIdx.x & 63;
  if (w >= N_NODES) return;
  int b = rowptr[w], e = rowptr[w + 1];
  float a0 = 0.f, a1 = 0.f;
  int j = b;
  for (; j + 1 < e; j += 2) {
    int s0 = esrc[j], s1 = esrc[j + 1];
    const float* r0 = h1p + (size_t)s0 * 128;
    const float* r1 = h1p + (size_t)s1 * 128;
    a0 += r0[lane];
    a1 += r0[lane + 64];
    a0 += r1[lane];
    a1 += r1[lane + 64];
  }
  if (j < e) {
    const float* r = h1p + (size_t)esrc[j] * 128;
    a0 += r[lane];
    a1 += r[lane + 64];
  }
  float dd = dinv[w];
  size_t o = (size_t)w * 128 + lane;
  out1[o]      += dd * a0;
  out1[o + 64] += dd * a1;
}

// h2p = (relu(out1) @ W2) * dinv ; out2 = (...) * dinv^2 + b2
__global__ __launch_bounds__(256) void k_gemm2(const float* __restrict__ out1,
                                               const float* __restrict__ W2,
                                               const float* __restrict__ b2,
                                               const float* __restrict__ dinv,
                                               float* __restrict__ h2p,
                                               float* __restrict__ out2) {
  __shared__ float Wl[128 * 64];
  __shared__ float xs[16][128];
  const int f = threadIdx.x & 63;
  const int q = threadIdx.x >> 6;
  const int n0 = blockIdx.x * 16;

  for (int i = threadIdx.x; i < 128 * 64; i += 256) Wl[i] = W2[i];
  for (int i = threadIdx.x; i < 16 * 128; i += 256) {
    int nn = i >> 7, kk = i & 127;
    xs[nn][kk] = fmaxf(out1[(size_t)(n0 + nn) * 128 + kk], 0.f);
  }
  __syncthreads();

  float acc[4] = {0.f, 0.f, 0.f, 0.f};
  for (int k = 0; k < 128; ++k) {
    float w = Wl[k * 64 + f];
    acc[0] += xs[q * 4 + 0][k] * w;
    acc[1] += xs[q * 4 + 1][k] * w;
    acc[2] += xs[q * 4 + 2][k] * w;
    acc[3] += xs[q * 4 + 3][k] * w;
  }
#pragma unroll
  for (int j = 0; j < 4; ++j) {
    int node = n0 + q * 4 + j;
    float dl = dinv[node];
    float vd = acc[j] * dl;
    h2p[(size_t)node * 64 + f]  = vd;
    out2[(size_t)node * 64 + f] = vd * dl + b2[f];
  }
}

// out2[n] += dinv[n] * sum h2p[s]  -- one wave per node, 1 f/lane
__global__ __launch_bounds__(256) void k_pull2(const int* __restrict__ rowptr,
                                               const int* __restrict__ esrc,
                                               const float* __restrict__ dinv,
                                               const float* __restrict__ h2p,
                                               float* __restrict__ out2) {
  int w = (blockIdx.x * 256 + threadIdx.x) >> 6;
  int lane = threadIdx.x & 63;
  if (w >= N_NODES) return;
  int b = rowptr[w], e = rowptr[w + 1];
  float a = 0.f;
  int j = b;
  for (; j + 1 < e; j += 2) {
    int s0 = esrc[j], s1 = esrc[j + 1];
    a += h2p[(size_t)s0 * 64 + lane];
    a += h2p[(size_t)s1 * 64 + lane];
  }
  if (j < e) a += h2p[(size_t)esrc[j] * 64 + lane];
  out2[(size_t)w * 64 + lane] += dinv[w] * a;
}

// logits[e] = dot(z[a[e]], z[b[e]]) over 64 dims -- one wave per edge
__global__ __launch_bounds__(256) void k_decode(const int* __restrict__ ia,
                                                const int* __restrict__ ib,
                                                const float* __restrict__ z,
                                                float* __restrict__ out, int M) {
  const int lane = threadIdx.x & 63;
  int w = blockIdx.x * 4 + (threadIdx.x >> 6);
  const int nw = gridDim.x * 4;
  for (int e = w; e < M; e += nw) {
    float v = z[(size_t)ia[e] * 64 + lane] * z[(size_t)ib[e] * 64 + lane];
    v += __shfl_down(v, 32, 64);
    v += __shfl_down(v, 16, 64);
    v += __shfl_down(v, 8, 64);
    v += __shfl_down(v, 4, 64);
    v += __shfl_down(v, 2, 64);
    v += __shfl_down(v, 1, 64);
    if (lane == 0) out[e] = v;
  }
}

extern "C" void kernel_launch(void* const* d_in, const int* in_sizes, int n_in,
                              void* d_out, int out_size, void* d_ws, size_t ws_size,
                              hipStream_t stream) {
  const float* x   = (const float*)d_in[0];
  const int*   ei  = (const int*)d_in[1];
  const int*   eli = (const int*)d_in[2];
  const float* W1  = (const float*)d_in[3];
  const float* b1  = (const float*)d_in[4];
  const float* W2  = (const float*)d_in[5];
  const float* b2  = (const float*)d_in[6];
  float* outp = (float*)d_out;

  const int E = in_sizes[1] / 2;   // 800000
  const int M = in_sizes[2] / 2;   // 200000
  const int* src = ei;
  const int* dst = ei + E;
  const int* la  = eli;
  const int* lb  = eli + M;

  float* ws     = (float*)d_ws;
  float* dinv   = ws;
  int*   rowptr = (int*)(ws + OFF_ROWPTR);
  int*   bsum   = (int*)(ws + OFF_BSUM);
  int*   boff   = (int*)(ws + OFF_BOFF);
  int*   cnt    = (int*)(ws + OFF_CNT);     // histogram, then fill cursor
  int*   esrc   = (int*)(ws + OFF_ESRC);
  float* h1p    = ws + OFF_H1;
  float* out1   = ws + OFF_OUT1;
  float* h2p    = ws + OFF_H1;              // reuse dead h1p region
  float* out2   = ws + OFF_H1 + 3200000;

  // --- CSR build + degree normalization ---
  k_zero <<<NB, 256, 0, stream>>>(cnt);
  k_hist <<<(E + 255) / 256, 256, 0, stream>>>(dst, E, cnt);
  k_scan1<<<NB, 256, 0, stream>>>(cnt, rowptr, bsum);
  k_scan2<<<1, 256, 0, stream>>>(bsum, boff);
  k_scan3<<<NB, 256, 0, stream>>>(rowptr, cnt, dinv, boff, E);
  k_fill <<<(E + 255) / 256, 256, 0, stream>>>(src, dst, E, rowptr, cnt, esrc);

  // --- layer 1 ---
  dim3 g1(3125, 2);
  k_gemm1<<<g1, 256, 0, stream>>>(x, W1, b1, dinv, h1p, out1);
  k_pull1<<<12500, 256, 0, stream>>>(rowptr, esrc, dinv, h1p, out1);

  // --- layer 2 ---
  k_gemm2<<<3125, 256, 0, stream>>>(out1, W2, b2, dinv, h2p, out2);
  k_pull2<<<12500, 256, 0, stream>>>(rowptr, esrc, dinv, h2p, out2);

  // --- decode ---
  k_decode<<<2048, 256, 0, stream>>>(la, lb, out2, outp, M);
}

// Round 4
// 346.728 us; speedup vs baseline: 2.1075x; 1.1009x over previous
//
#include <hip/hip_runtime.h>

#define N_NODES 50000
#define NB ((N_NODES + 255) / 256)   // 196 scan blocks

// Workspace layout (4-byte units):
//   dinv   [0,       50000)   float
//   rowptr [50048,  100049)   int   (50001)
//   bsum   [100096, 100352)   int
//   boff   [100352, 100608)   int
//   cnt    [100608, 150608)   int   (histogram, then fill cursor)
//   esrc   [150656, 950656)   int
//   h1b    [950784, +3200000)  bf16 50000x128 (= h1*dinv[n]); later reused as h2b 50000x64
//   out1   [4150784, +6400000) float 50000x128
//   out2   [10550784,+3200000) float 50000x64
// total = 13,750,784 floats = 55.0 MB

#define OFF_ROWPTR 50048
#define OFF_BSUM   100096
#define OFF_BOFF   100352
#define OFF_CNT    100608
#define OFF_ESRC   150656
#define OFF_H1B    950784
#define OFF_OUT1   4150784
#define OFF_OUT2   10550784

__device__ __forceinline__ ushort f2bf(float f) {
  uint u = __float_as_uint(f);
  u += 0x7fffu + ((u >> 16) & 1u);   // RNE
  return (ushort)(u >> 16);
}
__device__ __forceinline__ uint pack2(float a, float b) {
  return (uint)f2bf(a) | ((uint)f2bf(b) << 16);
}

// ---------------- CSR build ----------------
__global__ __launch_bounds__(256) void k_zero(int* __restrict__ cnt) {
  int i = blockIdx.x * 256 + threadIdx.x;
  if (i < N_NODES) cnt[i] = 0;
}

__global__ __launch_bounds__(256) void k_hist(const int* __restrict__ dst, int E,
                                              int* __restrict__ cnt) {
  int i = blockIdx.x * 256 + threadIdx.x;
  if (i < E) atomicAdd(&cnt[dst[i]], 1);
}

__global__ __launch_bounds__(256) void k_scan1(const int* __restrict__ cnt,
                                               int* __restrict__ rowptr,
                                               int* __restrict__ bsum) {
  __shared__ int tmp[256];
  int i = blockIdx.x * 256 + threadIdx.x;
  int v = (i < N_NODES) ? cnt[i] : 0;
  tmp[threadIdx.x] = v;
  __syncthreads();
  for (int off = 1; off < 256; off <<= 1) {
    int t = (threadIdx.x >= off) ? tmp[threadIdx.x - off] : 0;
    __syncthreads();
    tmp[threadIdx.x] += t;
    __syncthreads();
  }
  if (i < N_NODES) rowptr[i] = tmp[threadIdx.x] - v;
  if (threadIdx.x == 255) bsum[blockIdx.x] = tmp[255];
}

__global__ __launch_bounds__(256) void k_scan2(const int* __restrict__ bsum,
                                               int* __restrict__ boff) {
  __shared__ int tmp[256];
  int v = (threadIdx.x < NB) ? bsum[threadIdx.x] : 0;
  tmp[threadIdx.x] = v;
  __syncthreads();
  for (int off = 1; off < 256; off <<= 1) {
    int t = (threadIdx.x >= off) ? tmp[threadIdx.x - off] : 0;
    __syncthreads();
    tmp[threadIdx.x] += t;
    __syncthreads();
  }
  if (threadIdx.x < NB) boff[threadIdx.x] = tmp[threadIdx.x] - v;
}

__global__ __launch_bounds__(256) void k_scan3(int* __restrict__ rowptr,
                                               int* __restrict__ cnt,
                                               float* __restrict__ dinv,
                                               const int* __restrict__ boff, int E) {
  int i = blockIdx.x * 256 + threadIdx.x;
  if (i < N_NODES) {
    rowptr[i] += boff[blockIdx.x];
    dinv[i] = rsqrtf(1.0f + (float)cnt[i]);
    cnt[i] = 0;
  }
  if (i == 0) rowptr[N_NODES] = E;
}

__global__ __launch_bounds__(256) void k_fill(const int* __restrict__ src,
                                              const int* __restrict__ dst, int E,
                                              const int* __restrict__ rowptr,
                                              int* __restrict__ cursor,
                                              int* __restrict__ esrc) {
  int e = blockIdx.x * 256 + threadIdx.x;
  if (e < E) {
    int d = dst[e];
    int pos = atomicAdd(&cursor[d], 1);
    esrc[rowptr[d] + pos] = src[e];
  }
}

// ---------------- layer 1 GEMM: h1b = bf16((x @ W1) * dinv[n]) ----------------
// 782 blocks x 256 thr; tile 64 nodes x 128 cols; K tiled by 64.
// thread = 4 nodes x 8 cols; inner 4k: 4+8 ds_read_b128 per 128 FMA.
__global__ __launch_bounds__(256) void k_gemm1(const float* __restrict__ x,
                                               const float* __restrict__ W1,
                                               const float* __restrict__ dinv,
                                               ushort* __restrict__ h1b) {
  __shared__ float Wl[64 * 128];   // 32 KB  Wl[k][c]
  __shared__ float xs[64 * 68];    // 17 KB  xs[n][k], pad 68 -> 2-way max
  const int tid = threadIdx.x;
  const int lane = tid & 63;
  const int wv = tid >> 6;
  const int cg = lane & 15;
  const int ng = wv * 4 + (lane >> 4);   // 0..15
  const int n0 = blockIdx.x * 64;
  const int c0 = cg * 4;

  float acc[4][8];
#pragma unroll
  for (int j = 0; j < 4; ++j)
#pragma unroll
    for (int c = 0; c < 8; ++c) acc[j][c] = 0.f;

  for (int kt = 0; kt < 2; ++kt) {
    for (int i = tid; i < 64 * 16; i += 256) {
      int nn = i >> 4, kq = i & 15;
      int gr = min(n0 + nn, N_NODES - 1);
      *(float4*)&xs[nn * 68 + kq * 4] =
          *(const float4*)&x[(size_t)gr * 128 + kt * 64 + kq * 4];
    }
    for (int i = tid; i < 64 * 32; i += 256) {
      int kk = i >> 5, cq = i & 31;
      *(float4*)&Wl[kk * 128 + cq * 4] =
          *(const float4*)&W1[(size_t)(kt * 64 + kk) * 128 + cq * 4];
    }
    __syncthreads();

    for (int k4 = 0; k4 < 64; k4 += 4) {
      float4 xa[4];
#pragma unroll
      for (int j = 0; j < 4; ++j)
        xa[j] = *(const float4*)&xs[(ng * 4 + j) * 68 + k4];
#pragma unroll
      for (int i = 0; i < 4; ++i) {
        float4 w0 = *(const float4*)&Wl[(k4 + i) * 128 + c0];
        float4 w1 = *(const float4*)&Wl[(k4 + i) * 128 + 64 + c0];
#pragma unroll
        for (int j = 0; j < 4; ++j) {
          float xv = i == 0 ? xa[j].x : i == 1 ? xa[j].y : i == 2 ? xa[j].z : xa[j].w;
          acc[j][0] = fmaf(xv, w0.x, acc[j][0]);
          acc[j][1] = fmaf(xv, w0.y, acc[j][1]);
          acc[j][2] = fmaf(xv, w0.z, acc[j][2]);
          acc[j][3] = fmaf(xv, w0.w, acc[j][3]);
          acc[j][4] = fmaf(xv, w1.x, acc[j][4]);
          acc[j][5] = fmaf(xv, w1.y, acc[j][5]);
          acc[j][6] = fmaf(xv, w1.z, acc[j][6]);
          acc[j][7] = fmaf(xv, w1.w, acc[j][7]);
        }
      }
    }
    __syncthreads();
  }

#pragma unroll
  for (int j = 0; j < 4; ++j) {
    int n = n0 + ng * 4 + j;
    if (n >= N_NODES) continue;
    float dl = dinv[n];
    uint2 p0, p1;
    p0.x = pack2(acc[j][0] * dl, acc[j][1] * dl);
    p0.y = pack2(acc[j][2] * dl, acc[j][3] * dl);
    p1.x = pack2(acc[j][4] * dl, acc[j][5] * dl);
    p1.y = pack2(acc[j][6] * dl, acc[j][7] * dl);
    *(uint2*)&h1b[(size_t)n * 128 + c0]      = p0;
    *(uint2*)&h1b[(size_t)n * 128 + 64 + c0] = p1;
  }
}

// out1[n] = dinv[n]*(h1b[n] + sum_{s in in(n)} h1b[s]) + b1  -- wave/node, 2 f/lane
__global__ __launch_bounds__(256) void k_pull1(const int* __restrict__ rowptr,
                                               const int* __restrict__ esrc,
                                               const float* __restrict__ dinv,
                                               const uint* __restrict__ h1b,
                                               const float* __restrict__ b1,
                                               float* __restrict__ out1) {
  int n = (blockIdx.x * 256 + threadIdx.x) >> 6;
  int lane = threadIdx.x & 63;
  if (n >= N_NODES) return;
  int b = rowptr[n], e = rowptr[n + 1];
  uint u = h1b[(size_t)n * 64 + lane];   // self-loop term
  float a0 = __uint_as_float(u << 16);
  float a1 = __uint_as_float(u & 0xffff0000u);
  int j = b;
  for (; j + 1 < e; j += 2) {
    uint u0 = h1b[(size_t)esrc[j] * 64 + lane];
    uint u1 = h1b[(size_t)esrc[j + 1] * 64 + lane];
    a0 += __uint_as_float(u0 << 16);
    a1 += __uint_as_float(u0 & 0xffff0000u);
    a0 += __uint_as_float(u1 << 16);
    a1 += __uint_as_float(u1 & 0xffff0000u);
  }
  if (j < e) {
    uint u2 = h1b[(size_t)esrc[j] * 64 + lane];
    a0 += __uint_as_float(u2 << 16);
    a1 += __uint_as_float(u2 & 0xffff0000u);
  }
  float dd = dinv[n];
  float2 bb = ((const float2*)b1)[lane];
  float2 o;
  o.x = fmaf(dd, a0, bb.x);
  o.y = fmaf(dd, a1, bb.y);
  ((float2*)out1)[(size_t)n * 64 + lane] = o;
}

// ---------------- layer 2 GEMM: h2b = bf16((relu(out1) @ W2) * dinv[n]) ------
__global__ __launch_bounds__(256) void k_gemm2(const float* __restrict__ out1,
                                               const float* __restrict__ W2,
                                               const float* __restrict__ dinv,
                                               ushort* __restrict__ h2b) {
  __shared__ float Wl[64 * 64];    // 16 KB
  __shared__ float xs[64 * 68];    // 17 KB
  const int tid = threadIdx.x;
  const int lane = tid & 63;
  const int wv = tid >> 6;
  const int cg = lane & 15;
  const int ng = wv * 4 + (lane >> 4);
  const int n0 = blockIdx.x * 64;
  const int c0 = cg * 4;

  float acc[4][4];
#pragma unroll
  for (int j = 0; j < 4; ++j)
#pragma unroll
    for (int c = 0; c < 4; ++c) acc[j][c] = 0.f;

  for (int kt = 0; kt < 2; ++kt) {
    for (int i = tid; i < 64 * 16; i += 256) {
      int nn = i >> 4, kq = i & 15;
      int gr = min(n0 + nn, N_NODES - 1);
      float4 v = *(const float4*)&out1[(size_t)gr * 128 + kt * 64 + kq * 4];
      v.x = fmaxf(v.x, 0.f); v.y = fmaxf(v.y, 0.f);
      v.z = fmaxf(v.z, 0.f); v.w = fmaxf(v.w, 0.f);
      *(float4*)&xs[nn * 68 + kq * 4] = v;
    }
    for (int i = tid; i < 64 * 16; i += 256) {
      int kk = i >> 4, cq = i & 15;
      *(float4*)&Wl[kk * 64 + cq * 4] =
          *(const float4*)&W2[(size_t)(kt * 64 + kk) * 64 + cq * 4];
    }
    __syncthreads();

    for (int k4 = 0; k4 < 64; k4 += 4) {
      float4 xa[4];
#pragma unroll
      for (int j = 0; j < 4; ++j)
        xa[j] = *(const float4*)&xs[(ng * 4 + j) * 68 + k4];
#pragma unroll
      for (int i = 0; i < 4; ++i) {
        float4 w0 = *(const float4*)&Wl[(k4 + i) * 64 + c0];
#pragma unroll
        for (int j = 0; j < 4; ++j) {
          float xv = i == 0 ? xa[j].x : i == 1 ? xa[j].y : i == 2 ? xa[j].z : xa[j].w;
          acc[j][0] = fmaf(xv, w0.x, acc[j][0]);
          acc[j][1] = fmaf(xv, w0.y, acc[j][1]);
          acc[j][2] = fmaf(xv, w0.z, acc[j][2]);
          acc[j][3] = fmaf(xv, w0.w, acc[j][3]);
        }
      }
    }
    __syncthreads();
  }

#pragma unroll
  for (int j = 0; j < 4; ++j) {
    int n = n0 + ng * 4 + j;
    if (n >= N_NODES) continue;
    float dl = dinv[n];
    uint2 p;
    p.x = pack2(acc[j][0] * dl, acc[j][1] * dl);
    p.y = pack2(acc[j][2] * dl, acc[j][3] * dl);
    *(uint2*)&h2b[(size_t)n * 64 + c0] = p;
  }
}

// out2[n] = dinv[n]*(h2b[n] + sum h2b[s]) + b2  -- wave/node, 1 f/lane
__global__ __launch_bounds__(256) void k_pull2(const int* __restrict__ rowptr,
                                               const int* __restrict__ esrc,
                                               const float* __restrict__ dinv,
                                               const ushort* __restrict__ h2b,
                                               const float* __restrict__ b2,
                                               float* __restrict__ out2) {
  int n = (blockIdx.x * 256 + threadIdx.x) >> 6;
  int lane = threadIdx.x & 63;
  if (n >= N_NODES) return;
  int b = rowptr[n], e = rowptr[n + 1];
  float a = __uint_as_float((uint)h2b[(size_t)n * 64 + lane] << 16);  // self
  int j = b;
  for (; j + 1 < e; j += 2) {
    ushort v0 = h2b[(size_t)esrc[j] * 64 + lane];
    ushort v1 = h2b[(size_t)esrc[j + 1] * 64 + lane];
    a += __uint_as_float((uint)v0 << 16);
    a += __uint_as_float((uint)v1 << 16);
  }
  if (j < e) a += __uint_as_float((uint)h2b[(size_t)esrc[j] * 64 + lane] << 16);
  out2[(size_t)n * 64 + lane] = fmaf(dinv[n], a, b2[lane]);
}

// logits[e] = dot(z[a[e]], z[b[e]]) over 64 dims -- one wave per edge
__global__ __launch_bounds__(256) void k_decode(const int* __restrict__ ia,
                                                const int* __restrict__ ib,
                                                const float* __restrict__ z,
                                                float* __restrict__ out, int M) {
  const int lane = threadIdx.x & 63;
  int w = blockIdx.x * 4 + (threadIdx.x >> 6);
  const int nw = gridDim.x * 4;
  for (int e = w; e < M; e += nw) {
    float v = z[(size_t)ia[e] * 64 + lane] * z[(size_t)ib[e] * 64 + lane];
    v += __shfl_down(v, 32, 64);
    v += __shfl_down(v, 16, 64);
    v += __shfl_down(v, 8, 64);
    v += __shfl_down(v, 4, 64);
    v += __shfl_down(v, 2, 64);
    v += __shfl_down(v, 1, 64);
    if (lane == 0) out[e] = v;
  }
}

extern "C" void kernel_launch(void* const* d_in, const int* in_sizes, int n_in,
                              void* d_out, int out_size, void* d_ws, size_t ws_size,
                              hipStream_t stream) {
  const float* x   = (const float*)d_in[0];
  const int*   ei  = (const int*)d_in[1];
  const int*   eli = (const int*)d_in[2];
  const float* W1  = (const float*)d_in[3];
  const float* b1  = (const float*)d_in[4];
  const float* W2  = (const float*)d_in[5];
  const float* b2  = (const float*)d_in[6];
  float* outp = (float*)d_out;

  const int E = in_sizes[1] / 2;   // 800000
  const int M = in_sizes[2] / 2;   // 200000
  const int* src = ei;
  const int* dst = ei + E;
  const int* la  = eli;
  const int* lb  = eli + M;

  float* ws     = (float*)d_ws;
  float* dinv   = ws;
  int*   rowptr = (int*)(ws + OFF_ROWPTR);
  int*   bsum   = (int*)(ws + OFF_BSUM);
  int*   boff   = (int*)(ws + OFF_BOFF);
  int*   cnt    = (int*)(ws + OFF_CNT);
  int*   esrc   = (int*)(ws + OFF_ESRC);
  ushort* h1b   = (ushort*)(ws + OFF_H1B);
  ushort* h2b   = (ushort*)(ws + OFF_H1B);    // reuse (h1b dead after pull1)
  float* out1   = ws + OFF_OUT1;
  float* out2   = ws + OFF_OUT2;

  // CSR build + degree norm
  k_zero <<<NB, 256, 0, stream>>>(cnt);
  k_hist <<<(E + 255) / 256, 256, 0, stream>>>(dst, E, cnt);
  k_scan1<<<NB, 256, 0, stream>>>(cnt, rowptr, bsum);
  k_scan2<<<1, 256, 0, stream>>>(bsum, boff);
  k_scan3<<<NB, 256, 0, stream>>>(rowptr, cnt, dinv, boff, E);
  k_fill <<<(E + 255) / 256, 256, 0, stream>>>(src, dst, E, rowptr, cnt, esrc);

  // layer 1
  k_gemm1<<<(N_NODES + 63) / 64, 256, 0, stream>>>(x, W1, dinv, h1b);
  k_pull1<<<12500, 256, 0, stream>>>(rowptr, esrc, dinv, (const uint*)h1b, b1, out1);

  // layer 2
  k_gemm2<<<(N_NODES + 63) / 64, 256, 0, stream>>>(out1, W2, dinv, h2b);
  k_pull2<<<12500, 256, 0, stream>>>(rowptr, esrc, dinv, h2b, b2, out2);

  // decode
  k_decode<<<2048, 256, 0, stream>>>(la, lb, out2, outp, M);
}

// Round 5
// 262.198 us; speedup vs baseline: 2.7869x; 1.3224x over previous
//
#include <hip/hip_runtime.h>

#define N_NODES 50000
#define NB ((N_NODES + 255) / 256)   // 196 scan blocks

// Workspace layout (4-byte units):
//   dinv   [0,       50000)    float
//   rowptr [50048,  100049)    int (50001)
//   bsum   [100096, 100352)    int
//   boff   [100352, 100608)    int
//   cnt    [100608, 150608)    int (in-degree histogram)
//   esrc   [150656, 950656)    int (src per CSR slot)
//   epos   [950656, 1750656)   int (within-bucket position per edge)
//   h1b    [1750784, +3200000) bf16 50000x128 (=h1*dinv); reused as h2b 50000x64
//   out1   [4950784, +6400000) float 50000x128
//   out2   [11350784,+3200000) float 50000x64
// total = 14,550,784 floats = 58.2 MB

#define OFF_ROWPTR 50048
#define OFF_BSUM   100096
#define OFF_BOFF   100352
#define OFF_CNT    100608
#define OFF_ESRC   150656
#define OFF_EPOS   950656
#define OFF_H1B    1750784
#define OFF_OUT1   4950784
#define OFF_OUT2   11350784

__device__ __forceinline__ ushort f2bf(float f) {
  uint u = __float_as_uint(f);
  u += 0x7fffu + ((u >> 16) & 1u);   // RNE
  return (ushort)(u >> 16);
}
__device__ __forceinline__ uint pack2(float a, float b) {
  return (uint)f2bf(a) | ((uint)f2bf(b) << 16);
}
__device__ __forceinline__ float blo(uint u) { return __uint_as_float(u << 16); }
__device__ __forceinline__ float bhi(uint u) { return __uint_as_float(u & 0xffff0000u); }

// ---------------- CSR build ----------------
__global__ __launch_bounds__(256) void k_zero(int* __restrict__ cnt) {
  int i = blockIdx.x * 256 + threadIdx.x;
  if (i < N_NODES) cnt[i] = 0;
}

// histogram + remember each edge's position within its dst bucket
__global__ __launch_bounds__(256) void k_hist(const int* __restrict__ dst, int E,
                                              int* __restrict__ cnt,
                                              int* __restrict__ epos) {
  int i = blockIdx.x * 256 + threadIdx.x;
  if (i < E) epos[i] = atomicAdd(&cnt[dst[i]], 1);
}

__global__ __launch_bounds__(256) void k_scan1(const int* __restrict__ cnt,
                                               int* __restrict__ rowptr,
                                               int* __restrict__ bsum) {
  __shared__ int tmp[256];
  int i = blockIdx.x * 256 + threadIdx.x;
  int v = (i < N_NODES) ? cnt[i] : 0;
  tmp[threadIdx.x] = v;
  __syncthreads();
  for (int off = 1; off < 256; off <<= 1) {
    int t = (threadIdx.x >= off) ? tmp[threadIdx.x - off] : 0;
    __syncthreads();
    tmp[threadIdx.x] += t;
    __syncthreads();
  }
  if (i < N_NODES) rowptr[i] = tmp[threadIdx.x] - v;
  if (threadIdx.x == 255) bsum[blockIdx.x] = tmp[255];
}

__global__ __launch_bounds__(256) void k_scan2(const int* __restrict__ bsum,
                                               int* __restrict__ boff) {
  __shared__ int tmp[256];
  int v = (threadIdx.x < NB) ? bsum[threadIdx.x] : 0;
  tmp[threadIdx.x] = v;
  __syncthreads();
  for (int off = 1; off < 256; off <<= 1) {
    int t = (threadIdx.x >= off) ? tmp[threadIdx.x - off] : 0;
    __syncthreads();
    tmp[threadIdx.x] += t;
    __syncthreads();
  }
  if (threadIdx.x < NB) boff[threadIdx.x] = tmp[threadIdx.x] - v;
}

__global__ __launch_bounds__(256) void k_scan3(int* __restrict__ rowptr,
                                               const int* __restrict__ cnt,
                                               float* __restrict__ dinv,
                                               const int* __restrict__ boff, int E) {
  int i = blockIdx.x * 256 + threadIdx.x;
  if (i < N_NODES) {
    rowptr[i] += boff[blockIdx.x];
    dinv[i] = rsqrtf(1.0f + (float)cnt[i]);
  }
  if (i == 0) rowptr[N_NODES] = E;
}

// pure scatter, no atomics
__global__ __launch_bounds__(256) void k_fill(const int* __restrict__ src,
                                              const int* __restrict__ dst,
                                              const int* __restrict__ epos, int E,
                                              const int* __restrict__ rowptr,
                                              int* __restrict__ esrc) {
  int e = blockIdx.x * 256 + threadIdx.x;
  if (e < E) esrc[rowptr[dst[e]] + epos[e]] = src[e];
}

// ---------------- layer 1 GEMM: h1b = bf16((x @ W1) * dinv[n]) ----------------
__global__ __launch_bounds__(256) void k_gemm1(const float* __restrict__ x,
                                               const float* __restrict__ W1,
                                               const float* __restrict__ dinv,
                                               ushort* __restrict__ h1b) {
  __shared__ float Wl[64 * 128];
  __shared__ float xs[64 * 68];
  const int tid = threadIdx.x;
  const int lane = tid & 63;
  const int wv = tid >> 6;
  const int cg = lane & 15;
  const int ng = wv * 4 + (lane >> 4);
  const int n0 = blockIdx.x * 64;
  const int c0 = cg * 4;

  float acc[4][8];
#pragma unroll
  for (int j = 0; j < 4; ++j)
#pragma unroll
    for (int c = 0; c < 8; ++c) acc[j][c] = 0.f;

  for (int kt = 0; kt < 2; ++kt) {
    for (int i = tid; i < 64 * 16; i += 256) {
      int nn = i >> 4, kq = i & 15;
      int gr = min(n0 + nn, N_NODES - 1);
      *(float4*)&xs[nn * 68 + kq * 4] =
          *(const float4*)&x[(size_t)gr * 128 + kt * 64 + kq * 4];
    }
    for (int i = tid; i < 64 * 32; i += 256) {
      int kk = i >> 5, cq = i & 31;
      *(float4*)&Wl[kk * 128 + cq * 4] =
          *(const float4*)&W1[(size_t)(kt * 64 + kk) * 128 + cq * 4];
    }
    __syncthreads();

    for (int k4 = 0; k4 < 64; k4 += 4) {
      float4 xa[4];
#pragma unroll
      for (int j = 0; j < 4; ++j)
        xa[j] = *(const float4*)&xs[(ng * 4 + j) * 68 + k4];
#pragma unroll
      for (int i = 0; i < 4; ++i) {
        float4 w0 = *(const float4*)&Wl[(k4 + i) * 128 + c0];
        float4 w1 = *(const float4*)&Wl[(k4 + i) * 128 + 64 + c0];
#pragma unroll
        for (int j = 0; j < 4; ++j) {
          float xv = i == 0 ? xa[j].x : i == 1 ? xa[j].y : i == 2 ? xa[j].z : xa[j].w;
          acc[j][0] = fmaf(xv, w0.x, acc[j][0]);
          acc[j][1] = fmaf(xv, w0.y, acc[j][1]);
          acc[j][2] = fmaf(xv, w0.z, acc[j][2]);
          acc[j][3] = fmaf(xv, w0.w, acc[j][3]);
          acc[j][4] = fmaf(xv, w1.x, acc[j][4]);
          acc[j][5] = fmaf(xv, w1.y, acc[j][5]);
          acc[j][6] = fmaf(xv, w1.z, acc[j][6]);
          acc[j][7] = fmaf(xv, w1.w, acc[j][7]);
        }
      }
    }
    __syncthreads();
  }

#pragma unroll
  for (int j = 0; j < 4; ++j) {
    int n = n0 + ng * 4 + j;
    if (n >= N_NODES) continue;
    float dl = dinv[n];
    uint2 p0, p1;
    p0.x = pack2(acc[j][0] * dl, acc[j][1] * dl);
    p0.y = pack2(acc[j][2] * dl, acc[j][3] * dl);
    p1.x = pack2(acc[j][4] * dl, acc[j][5] * dl);
    p1.y = pack2(acc[j][6] * dl, acc[j][7] * dl);
    *(uint2*)&h1b[(size_t)n * 128 + c0]      = p0;
    *(uint2*)&h1b[(size_t)n * 128 + 64 + c0] = p1;
  }
}

// out1[n] = dinv[n]*(h1b[n] + sum_{s} h1b[s]) + b1
// wave/node; neighbor indices cached in a register, broadcast via shfl; unroll 8.
__global__ __launch_bounds__(256) void k_pull1(const int* __restrict__ rowptr,
                                               const int* __restrict__ esrc,
                                               const float* __restrict__ dinv,
                                               const uint* __restrict__ h1b,
                                               const float* __restrict__ b1,
                                               float* __restrict__ out1) {
  int n = (blockIdx.x * 256 + threadIdx.x) >> 6;
  int lane = threadIdx.x & 63;
  if (n >= N_NODES) return;
  int b = rowptr[n], e = rowptr[n + 1];
  int deg = e - b;

  uint u = h1b[(size_t)n * 64 + lane];   // self-loop
  float a0 = blo(u), a1 = bhi(u);

  int sidx = (lane < deg) ? esrc[b + lane] : 0;  // up to 64 indices, 1 load
  int kmax = deg < 64 ? deg : 64;
  int k = 0;
  for (; k + 7 < kmax; k += 8) {
    int s0 = __shfl(sidx, k + 0, 64), s1 = __shfl(sidx, k + 1, 64);
    int s2 = __shfl(sidx, k + 2, 64), s3 = __shfl(sidx, k + 3, 64);
    int s4 = __shfl(sidx, k + 4, 64), s5 = __shfl(sidx, k + 5, 64);
    int s6 = __shfl(sidx, k + 6, 64), s7 = __shfl(sidx, k + 7, 64);
    uint u0 = h1b[(size_t)s0 * 64 + lane];
    uint u1 = h1b[(size_t)s1 * 64 + lane];
    uint u2 = h1b[(size_t)s2 * 64 + lane];
    uint u3 = h1b[(size_t)s3 * 64 + lane];
    uint u4 = h1b[(size_t)s4 * 64 + lane];
    uint u5 = h1b[(size_t)s5 * 64 + lane];
    uint u6 = h1b[(size_t)s6 * 64 + lane];
    uint u7 = h1b[(size_t)s7 * 64 + lane];
    a0 += blo(u0) + blo(u1) + blo(u2) + blo(u3) + blo(u4) + blo(u5) + blo(u6) + blo(u7);
    a1 += bhi(u0) + bhi(u1) + bhi(u2) + bhi(u3) + bhi(u4) + bhi(u5) + bhi(u6) + bhi(u7);
  }
  for (; k < kmax; ++k) {
    int s = __shfl(sidx, k, 64);
    uint uu = h1b[(size_t)s * 64 + lane];
    a0 += blo(uu);
    a1 += bhi(uu);
  }
  for (int j = b + 64; j < e; ++j) {   // deg > 64: astronomically rare, correct anyway
    uint uu = h1b[(size_t)esrc[j] * 64 + lane];
    a0 += blo(uu);
    a1 += bhi(uu);
  }

  float dd = dinv[n];
  float2 bb = ((const float2*)b1)[lane];
  float2 o;
  o.x = fmaf(dd, a0, bb.x);
  o.y = fmaf(dd, a1, bb.y);
  ((float2*)out1)[(size_t)n * 64 + lane] = o;
}

// ---------------- layer 2 GEMM: h2b = bf16((relu(out1) @ W2) * dinv[n]) ------
__global__ __launch_bounds__(256) void k_gemm2(const float* __restrict__ out1,
                                               const float* __restrict__ W2,
                                               const float* __restrict__ dinv,
                                               ushort* __restrict__ h2b) {
  __shared__ float Wl[64 * 64];
  __shared__ float xs[64 * 68];
  const int tid = threadIdx.x;
  const int lane = tid & 63;
  const int wv = tid >> 6;
  const int cg = lane & 15;
  const int ng = wv * 4 + (lane >> 4);
  const int n0 = blockIdx.x * 64;
  const int c0 = cg * 4;

  float acc[4][4];
#pragma unroll
  for (int j = 0; j < 4; ++j)
#pragma unroll
    for (int c = 0; c < 4; ++c) acc[j][c] = 0.f;

  for (int kt = 0; kt < 2; ++kt) {
    for (int i = tid; i < 64 * 16; i += 256) {
      int nn = i >> 4, kq = i & 15;
      int gr = min(n0 + nn, N_NODES - 1);
      float4 v = *(const float4*)&out1[(size_t)gr * 128 + kt * 64 + kq * 4];
      v.x = fmaxf(v.x, 0.f); v.y = fmaxf(v.y, 0.f);
      v.z = fmaxf(v.z, 0.f); v.w = fmaxf(v.w, 0.f);
      *(float4*)&xs[nn * 68 + kq * 4] = v;
    }
    for (int i = tid; i < 64 * 16; i += 256) {
      int kk = i >> 4, cq = i & 15;
      *(float4*)&Wl[kk * 64 + cq * 4] =
          *(const float4*)&W2[(size_t)(kt * 64 + kk) * 64 + cq * 4];
    }
    __syncthreads();

    for (int k4 = 0; k4 < 64; k4 += 4) {
      float4 xa[4];
#pragma unroll
      for (int j = 0; j < 4; ++j)
        xa[j] = *(const float4*)&xs[(ng * 4 + j) * 68 + k4];
#pragma unroll
      for (int i = 0; i < 4; ++i) {
        float4 w0 = *(const float4*)&Wl[(k4 + i) * 64 + c0];
#pragma unroll
        for (int j = 0; j < 4; ++j) {
          float xv = i == 0 ? xa[j].x : i == 1 ? xa[j].y : i == 2 ? xa[j].z : xa[j].w;
          acc[j][0] = fmaf(xv, w0.x, acc[j][0]);
          acc[j][1] = fmaf(xv, w0.y, acc[j][1]);
          acc[j][2] = fmaf(xv, w0.z, acc[j][2]);
          acc[j][3] = fmaf(xv, w0.w, acc[j][3]);
        }
      }
    }
    __syncthreads();
  }

#pragma unroll
  for (int j = 0; j < 4; ++j) {
    int n = n0 + ng * 4 + j;
    if (n >= N_NODES) continue;
    float dl = dinv[n];
    uint2 p;
    p.x = pack2(acc[j][0] * dl, acc[j][1] * dl);
    p.y = pack2(acc[j][2] * dl, acc[j][3] * dl);
    *(uint2*)&h2b[(size_t)n * 64 + c0] = p;
  }
}

// out2[n] = dinv[n]*(h2b[n] + sum h2b[s]) + b2  -- same shfl-broadcast + unroll 8
__global__ __launch_bounds__(256) void k_pull2(const int* __restrict__ rowptr,
                                               const int* __restrict__ esrc,
                                               const float* __restrict__ dinv,
                                               const ushort* __restrict__ h2b,
                                               const float* __restrict__ b2,
                                               float* __restrict__ out2) {
  int n = (blockIdx.x * 256 + threadIdx.x) >> 6;
  int lane = threadIdx.x & 63;
  if (n >= N_NODES) return;
  int b = rowptr[n], e = rowptr[n + 1];
  int deg = e - b;

  float a = __uint_as_float((uint)h2b[(size_t)n * 64 + lane] << 16);  // self

  int sidx = (lane < deg) ? esrc[b + lane] : 0;
  int kmax = deg < 64 ? deg : 64;
  int k = 0;
  for (; k + 7 < kmax; k += 8) {
    int s0 = __shfl(sidx, k + 0, 64), s1 = __shfl(sidx, k + 1, 64);
    int s2 = __shfl(sidx, k + 2, 64), s3 = __shfl(sidx, k + 3, 64);
    int s4 = __shfl(sidx, k + 4, 64), s5 = __shfl(sidx, k + 5, 64);
    int s6 = __shfl(sidx, k + 6, 64), s7 = __shfl(sidx, k + 7, 64);
    ushort v0 = h2b[(size_t)s0 * 64 + lane];
    ushort v1 = h2b[(size_t)s1 * 64 + lane];
    ushort v2 = h2b[(size_t)s2 * 64 + lane];
    ushort v3 = h2b[(size_t)s3 * 64 + lane];
    ushort v4 = h2b[(size_t)s4 * 64 + lane];
    ushort v5 = h2b[(size_t)s5 * 64 + lane];
    ushort v6 = h2b[(size_t)s6 * 64 + lane];
    ushort v7 = h2b[(size_t)s7 * 64 + lane];
    a += __uint_as_float((uint)v0 << 16) + __uint_as_float((uint)v1 << 16)
       + __uint_as_float((uint)v2 << 16) + __uint_as_float((uint)v3 << 16)
       + __uint_as_float((uint)v4 << 16) + __uint_as_float((uint)v5 << 16)
       + __uint_as_float((uint)v6 << 16) + __uint_as_float((uint)v7 << 16);
  }
  for (; k < kmax; ++k) {
    int s = __shfl(sidx, k, 64);
    a += __uint_as_float((uint)h2b[(size_t)s * 64 + lane] << 16);
  }
  for (int j = b + 64; j < e; ++j)
    a += __uint_as_float((uint)h2b[(size_t)esrc[j] * 64 + lane] << 16);

  out2[(size_t)n * 64 + lane] = fmaf(dinv[n], a, b2[lane]);
}

// logits[e] = dot(z[a],z[b]) over 64 dims -- 16 lanes/edge, float4/lane
__global__ __launch_bounds__(256) void k_decode(const int* __restrict__ ia,
                                                const int* __restrict__ ib,
                                                const float* __restrict__ z,
                                                float* __restrict__ out, int M) {
  const int sub = threadIdx.x & 15;
  int e = (blockIdx.x * 256 + threadIdx.x) >> 4;
  if (e >= M) return;
  int a = ia[e], b = ib[e];
  float4 va = ((const float4*)z)[(size_t)a * 16 + sub];
  float4 vb = ((const float4*)z)[(size_t)b * 16 + sub];
  float v = va.x * vb.x + va.y * vb.y + va.z * vb.z + va.w * vb.w;
  v += __shfl_xor(v, 8, 64);
  v += __shfl_xor(v, 4, 64);
  v += __shfl_xor(v, 2, 64);
  v += __shfl_xor(v, 1, 64);
  if (sub == 0) out[e] = v;
}

extern "C" void kernel_launch(void* const* d_in, const int* in_sizes, int n_in,
                              void* d_out, int out_size, void* d_ws, size_t ws_size,
                              hipStream_t stream) {
  const float* x   = (const float*)d_in[0];
  const int*   ei  = (const int*)d_in[1];
  const int*   eli = (const int*)d_in[2];
  const float* W1  = (const float*)d_in[3];
  const float* b1  = (const float*)d_in[4];
  const float* W2  = (const float*)d_in[5];
  const float* b2  = (const float*)d_in[6];
  float* outp = (float*)d_out;

  const int E = in_sizes[1] / 2;   // 800000
  const int M = in_sizes[2] / 2;   // 200000
  const int* src = ei;
  const int* dst = ei + E;
  const int* la  = eli;
  const int* lb  = eli + M;

  float* ws     = (float*)d_ws;
  float* dinv   = ws;
  int*   rowptr = (int*)(ws + OFF_ROWPTR);
  int*   bsum   = (int*)(ws + OFF_BSUM);
  int*   boff   = (int*)(ws + OFF_BOFF);
  int*   cnt    = (int*)(ws + OFF_CNT);
  int*   esrc   = (int*)(ws + OFF_ESRC);
  int*   epos   = (int*)(ws + OFF_EPOS);
  ushort* h1b   = (ushort*)(ws + OFF_H1B);
  ushort* h2b   = (ushort*)(ws + OFF_H1B);   // reuse (h1b dead after pull1)
  float* out1   = ws + OFF_OUT1;
  float* out2   = ws + OFF_OUT2;

  // CSR build + degree norm
  k_zero <<<NB, 256, 0, stream>>>(cnt);
  k_hist <<<(E + 255) / 256, 256, 0, stream>>>(dst, E, cnt, epos);
  k_scan1<<<NB, 256, 0, stream>>>(cnt, rowptr, bsum);
  k_scan2<<<1, 256, 0, stream>>>(bsum, boff);
  k_scan3<<<NB, 256, 0, stream>>>(rowptr, cnt, dinv, boff, E);
  k_fill <<<(E + 255) / 256, 256, 0, stream>>>(src, dst, epos, E, rowptr, esrc);

  // layer 1
  k_gemm1<<<(N_NODES + 63) / 64, 256, 0, stream>>>(x, W1, dinv, h1b);
  k_pull1<<<12500, 256, 0, stream>>>(rowptr, esrc, dinv, (const uint*)h1b, b1, out1);

  // layer 2
  k_gemm2<<<(N_NODES + 63) / 64, 256, 0, stream>>>(out1, W2, dinv, h2b);
  k_pull2<<<12500, 256, 0, stream>>>(rowptr, esrc, dinv, h2b, b2, out2);

  // decode
  k_decode<<<12500, 256, 0, stream>>>(la, lb, out2, outp, M);
}

// Round 6
// 234.703 us; speedup vs baseline: 3.1134x; 1.1171x over previous
//
#include <hip/hip_runtime.h>

#define N_NODES 50000
#define NB ((N_NODES + 255) / 256)   // 196 scan blocks

using half8 = __attribute__((ext_vector_type(8))) _Float16;
using half4 = __attribute__((ext_vector_type(4))) _Float16;
using f32x4 = __attribute__((ext_vector_type(4))) float;

// Workspace layout (4-byte units):
//   dinv   [0,       50000)    float
//   rowptr [50048,  100049)    int (50001)
//   bsum   [100096, 100352)    int
//   boff   [100352, 100608)    int
//   cnt    [100608, 150608)    int (in-degree histogram)
//   esrc   [150656, 950656)    int (src per CSR slot)
//   epos   [950656, 1750656)   int (within-bucket position per edge)
//   W1t    [1750656, +8192)    fp16 [128c][128k] transposed+swizzled
//   W2t    [1758848, +4096)    fp16 [64c][128k]  transposed+swizzled
//   h1b    [1762944, +3200000) bf16 50000x128 (=h1*dinv); reused as h2b 50000x64
//   out1   [4962944, +6400000) float 50000x128
//   out2   [11362944,+3200000) float 50000x64
// total = 14,562,944 floats = 58.3 MB

#define OFF_ROWPTR 50048
#define OFF_BSUM   100096
#define OFF_BOFF   100352
#define OFF_CNT    100608
#define OFF_ESRC   150656
#define OFF_EPOS   950656
#define OFF_W1T    1750656
#define OFF_W2T    1758848
#define OFF_H1B    1762944
#define OFF_OUT1   4962944
#define OFF_OUT2   11362944

__device__ __forceinline__ ushort f2bf(float f) {
  uint u = __float_as_uint(f);
  u += 0x7fffu + ((u >> 16) & 1u);   // RNE
  return (ushort)(u >> 16);
}
__device__ __forceinline__ uint pack2(float a, float b) {
  return (uint)f2bf(a) | ((uint)f2bf(b) << 16);
}
__device__ __forceinline__ float blo(uint u) { return __uint_as_float(u << 16); }
__device__ __forceinline__ float bhi(uint u) { return __uint_as_float(u & 0xffff0000u); }

// ---------------- CSR build ----------------
__global__ __launch_bounds__(256) void k_zero(int* __restrict__ cnt) {
  int i = blockIdx.x * 256 + threadIdx.x;
  if (i < N_NODES) cnt[i] = 0;
}

__global__ __launch_bounds__(256) void k_hist(const int* __restrict__ dst, int E,
                                              int* __restrict__ cnt,
                                              int* __restrict__ epos) {
  int i = blockIdx.x * 256 + threadIdx.x;
  if (i < E) epos[i] = atomicAdd(&cnt[dst[i]], 1);
}

__global__ __launch_bounds__(256) void k_scan1(const int* __restrict__ cnt,
                                               int* __restrict__ rowptr,
                                               int* __restrict__ bsum) {
  __shared__ int tmp[256];
  int i = blockIdx.x * 256 + threadIdx.x;
  int v = (i < N_NODES) ? cnt[i] : 0;
  tmp[threadIdx.x] = v;
  __syncthreads();
  for (int off = 1; off < 256; off <<= 1) {
    int t = (threadIdx.x >= off) ? tmp[threadIdx.x - off] : 0;
    __syncthreads();
    tmp[threadIdx.x] += t;
    __syncthreads();
  }
  if (i < N_NODES) rowptr[i] = tmp[threadIdx.x] - v;
  if (threadIdx.x == 255) bsum[blockIdx.x] = tmp[255];
}

__global__ __launch_bounds__(256) void k_scan2(const int* __restrict__ bsum,
                                               int* __restrict__ boff) {
  __shared__ int tmp[256];
  int v = (threadIdx.x < NB) ? bsum[threadIdx.x] : 0;
  tmp[threadIdx.x] = v;
  __syncthreads();
  for (int off = 1; off < 256; off <<= 1) {
    int t = (threadIdx.x >= off) ? tmp[threadIdx.x - off] : 0;
    __syncthreads();
    tmp[threadIdx.x] += t;
    __syncthreads();
  }
  if (threadIdx.x < NB) boff[threadIdx.x] = tmp[threadIdx.x] - v;
}

__global__ __launch_bounds__(256) void k_scan3(int* __restrict__ rowptr,
                                               const int* __restrict__ cnt,
                                               float* __restrict__ dinv,
                                               const int* __restrict__ boff, int E) {
  int i = blockIdx.x * 256 + threadIdx.x;
  if (i < N_NODES) {
    rowptr[i] += boff[blockIdx.x];
    dinv[i] = rsqrtf(1.0f + (float)cnt[i]);
  }
  if (i == 0) rowptr[N_NODES] = E;
}

__global__ __launch_bounds__(256) void k_fill(const int* __restrict__ src,
                                              const int* __restrict__ dst,
                                              const int* __restrict__ epos, int E,
                                              const int* __restrict__ rowptr,
                                              int* __restrict__ esrc) {
  int e = blockIdx.x * 256 + threadIdx.x;
  if (e < E) esrc[rowptr[dst[e]] + epos[e]] = src[e];
}

// ---------------- weight prep: fp16, transposed, XOR-swizzled ----------------
// W1t[c][k ^ ((c&7)<<3)] = fp16(W1[k][c]);  W2t likewise.
__global__ __launch_bounds__(256) void k_prep(const float* __restrict__ W1,
                                              const float* __restrict__ W2,
                                              _Float16* __restrict__ W1t,
                                              _Float16* __restrict__ W2t) {
  int i = blockIdx.x * 256 + threadIdx.x;
  if (i < 16384) {
    int c = i >> 7, k = i & 127;
    W1t[c * 128 + (k ^ ((c & 7) << 3))] = (_Float16)W1[k * 128 + c];
  } else if (i < 24576) {
    int j = i - 16384;
    int c = j >> 7, k = j & 127;
    W2t[c * 128 + (k ^ ((c & 7) << 3))] = (_Float16)W2[k * 64 + c];
  }
}

// ---------------- layer 1 GEMM (MFMA f16): h1b = bf16((x @ W1) * dinv) -------
// block = 64 nodes x 128 cols, 4 waves; wave = 16 nodes x 128 cols.
// MFMA swapped: D[wcol][node] = Wt . x^T  -> lane stores 4 consecutive cols.
__global__ __launch_bounds__(256) void k_gemm1(const float* __restrict__ x,
                                               const _Float16* __restrict__ W1t,
                                               const float* __restrict__ dinv,
                                               ushort* __restrict__ h1b) {
  __shared__ _Float16 Wl[128 * 128];   // 32 KB (already swizzled in global)
  __shared__ _Float16 xs[64 * 128];    // 16 KB (swizzled here)
  const int tid = threadIdx.x;
  const int lane = tid & 63;
  const int wv = tid >> 6;
  const int n0 = blockIdx.x * 64;

  // stage W: linear 16B copy (layout pre-swizzled)
  for (int i = tid; i < 128 * 128 / 8; i += 256)
    *(float4*)&Wl[i * 8] = *(const float4*)&W1t[i * 8];
  // stage x: fp32 -> fp16, swizzled rows
  for (int i = tid; i < 64 * 32; i += 256) {
    int nn = i >> 5, k4 = (i & 31) * 4;
    int gr = min(n0 + nn, N_NODES - 1);
    float4 v = *(const float4*)&x[(size_t)gr * 128 + k4];
    half4 hv;
    hv[0] = (_Float16)v.x; hv[1] = (_Float16)v.y;
    hv[2] = (_Float16)v.z; hv[3] = (_Float16)v.w;
    *(half4*)&xs[nn * 128 + (k4 ^ ((nn & 7) << 3))] = hv;
  }
  __syncthreads();

  f32x4 acc[8];
#pragma unroll
  for (int c = 0; c < 8; ++c) acc[c] = (f32x4){0.f, 0.f, 0.f, 0.f};

  const int m15 = lane & 15;       // node within wave-tile / W-col within col-tile
  const int kc = lane >> 4;        // k-chunk 0..3
  const int xrow = wv * 16 + m15;

#pragma unroll
  for (int kt = 0; kt < 4; ++kt) {
    int e0 = kt * 32 + kc * 8;
    half8 bfrag = *(half8*)&xs[xrow * 128 + (e0 ^ ((xrow & 7) << 3))];
#pragma unroll
    for (int ct = 0; ct < 8; ++ct) {
      int wrow = ct * 16 + m15;
      half8 afrag = *(half8*)&Wl[wrow * 128 + (e0 ^ ((wrow & 7) << 3))];
      acc[ct] = __builtin_amdgcn_mfma_f32_16x16x32_f16(afrag, bfrag, acc[ct], 0, 0, 0);
    }
  }

  int n = n0 + wv * 16 + m15;
  if (n < N_NODES) {
    float dl = dinv[n];
#pragma unroll
    for (int ct = 0; ct < 8; ++ct) {
      int c = ct * 16 + kc * 4;
      uint2 p;
      p.x = pack2(acc[ct][0] * dl, acc[ct][1] * dl);
      p.y = pack2(acc[ct][2] * dl, acc[ct][3] * dl);
      *(uint2*)&h1b[(size_t)n * 128 + c] = p;
    }
  }
}

// out1[n] = dinv[n]*(h1b[n] + sum_{s} h1b[s]) + b1  -- shfl-broadcast, unroll 8
__global__ __launch_bounds__(256) void k_pull1(const int* __restrict__ rowptr,
                                               const int* __restrict__ esrc,
                                               const float* __restrict__ dinv,
                                               const uint* __restrict__ h1b,
                                               const float* __restrict__ b1,
                                               float* __restrict__ out1) {
  int n = (blockIdx.x * 256 + threadIdx.x) >> 6;
  int lane = threadIdx.x & 63;
  if (n >= N_NODES) return;
  int b = rowptr[n], e = rowptr[n + 1];
  int deg = e - b;

  uint u = h1b[(size_t)n * 64 + lane];   // self-loop
  float a0 = blo(u), a1 = bhi(u);

  int sidx = (lane < deg) ? esrc[b + lane] : 0;
  int kmax = deg < 64 ? deg : 64;
  int k = 0;
  for (; k + 7 < kmax; k += 8) {
    int s0 = __shfl(sidx, k + 0, 64), s1 = __shfl(sidx, k + 1, 64);
    int s2 = __shfl(sidx, k + 2, 64), s3 = __shfl(sidx, k + 3, 64);
    int s4 = __shfl(sidx, k + 4, 64), s5 = __shfl(sidx, k + 5, 64);
    int s6 = __shfl(sidx, k + 6, 64), s7 = __shfl(sidx, k + 7, 64);
    uint u0 = h1b[(size_t)s0 * 64 + lane];
    uint u1 = h1b[(size_t)s1 * 64 + lane];
    uint u2 = h1b[(size_t)s2 * 64 + lane];
    uint u3 = h1b[(size_t)s3 * 64 + lane];
    uint u4 = h1b[(size_t)s4 * 64 + lane];
    uint u5 = h1b[(size_t)s5 * 64 + lane];
    uint u6 = h1b[(size_t)s6 * 64 + lane];
    uint u7 = h1b[(size_t)s7 * 64 + lane];
    a0 += blo(u0) + blo(u1) + blo(u2) + blo(u3) + blo(u4) + blo(u5) + blo(u6) + blo(u7);
    a1 += bhi(u0) + bhi(u1) + bhi(u2) + bhi(u3) + bhi(u4) + bhi(u5) + bhi(u6) + bhi(u7);
  }
  for (; k < kmax; ++k) {
    int s = __shfl(sidx, k, 64);
    uint uu = h1b[(size_t)s * 64 + lane];
    a0 += blo(uu);
    a1 += bhi(uu);
  }
  for (int j = b + 64; j < e; ++j) {
    uint uu = h1b[(size_t)esrc[j] * 64 + lane];
    a0 += blo(uu);
    a1 += bhi(uu);
  }

  float dd = dinv[n];
  float2 bb = ((const float2*)b1)[lane];
  float2 o;
  o.x = fmaf(dd, a0, bb.x);
  o.y = fmaf(dd, a1, bb.y);
  ((float2*)out1)[(size_t)n * 64 + lane] = o;
}

// ---------------- layer 2 GEMM (MFMA f16): h2b = bf16((relu(out1)@W2)*dinv) --
__global__ __launch_bounds__(256) void k_gemm2(const float* __restrict__ out1,
                                               const _Float16* __restrict__ W2t,
                                               const float* __restrict__ dinv,
                                               ushort* __restrict__ h2b) {
  __shared__ _Float16 Wl[64 * 128];    // 16 KB
  __shared__ _Float16 xs[64 * 128];    // 16 KB
  const int tid = threadIdx.x;
  const int lane = tid & 63;
  const int wv = tid >> 6;
  const int n0 = blockIdx.x * 64;

  for (int i = tid; i < 64 * 128 / 8; i += 256)
    *(float4*)&Wl[i * 8] = *(const float4*)&W2t[i * 8];
  for (int i = tid; i < 64 * 32; i += 256) {
    int nn = i >> 5, k4 = (i & 31) * 4;
    int gr = min(n0 + nn, N_NODES - 1);
    float4 v = *(const float4*)&out1[(size_t)gr * 128 + k4];
    half4 hv;
    hv[0] = (_Float16)fmaxf(v.x, 0.f); hv[1] = (_Float16)fmaxf(v.y, 0.f);
    hv[2] = (_Float16)fmaxf(v.z, 0.f); hv[3] = (_Float16)fmaxf(v.w, 0.f);
    *(half4*)&xs[nn * 128 + (k4 ^ ((nn & 7) << 3))] = hv;
  }
  __syncthreads();

  f32x4 acc[4];
#pragma unroll
  for (int c = 0; c < 4; ++c) acc[c] = (f32x4){0.f, 0.f, 0.f, 0.f};

  const int m15 = lane & 15;
  const int kc = lane >> 4;
  const int xrow = wv * 16 + m15;

#pragma unroll
  for (int kt = 0; kt < 4; ++kt) {
    int e0 = kt * 32 + kc * 8;
    half8 bfrag = *(half8*)&xs[xrow * 128 + (e0 ^ ((xrow & 7) << 3))];
#pragma unroll
    for (int ct = 0; ct < 4; ++ct) {
      int wrow = ct * 16 + m15;
      half8 afrag = *(half8*)&Wl[wrow * 128 + (e0 ^ ((wrow & 7) << 3))];
      acc[ct] = __builtin_amdgcn_mfma_f32_16x16x32_f16(afrag, bfrag, acc[ct], 0, 0, 0);
    }
  }

  int n = n0 + wv * 16 + m15;
  if (n < N_NODES) {
    float dl = dinv[n];
#pragma unroll
    for (int ct = 0; ct < 4; ++ct) {
      int c = ct * 16 + kc * 4;
      uint2 p;
      p.x = pack2(acc[ct][0] * dl, acc[ct][1] * dl);
      p.y = pack2(acc[ct][2] * dl, acc[ct][3] * dl);
      *(uint2*)&h2b[(size_t)n * 64 + c] = p;
    }
  }
}

// out2[n] = dinv[n]*(h2b[n] + sum h2b[s]) + b2  -- shfl-broadcast, unroll 8
__global__ __launch_bounds__(256) void k_pull2(const int* __restrict__ rowptr,
                                               const int* __restrict__ esrc,
                                               const float* __restrict__ dinv,
                                               const ushort* __restrict__ h2b,
                                               const float* __restrict__ b2,
                                               float* __restrict__ out2) {
  int n = (blockIdx.x * 256 + threadIdx.x) >> 6;
  int lane = threadIdx.x & 63;
  if (n >= N_NODES) return;
  int b = rowptr[n], e = rowptr[n + 1];
  int deg = e - b;

  float a = __uint_as_float((uint)h2b[(size_t)n * 64 + lane] << 16);  // self

  int sidx = (lane < deg) ? esrc[b + lane] : 0;
  int kmax = deg < 64 ? deg : 64;
  int k = 0;
  for (; k + 7 < kmax; k += 8) {
    int s0 = __shfl(sidx, k + 0, 64), s1 = __shfl(sidx, k + 1, 64);
    int s2 = __shfl(sidx, k + 2, 64), s3 = __shfl(sidx, k + 3, 64);
    int s4 = __shfl(sidx, k + 4, 64), s5 = __shfl(sidx, k + 5, 64);
    int s6 = __shfl(sidx, k + 6, 64), s7 = __shfl(sidx, k + 7, 64);
    ushort v0 = h2b[(size_t)s0 * 64 + lane];
    ushort v1 = h2b[(size_t)s1 * 64 + lane];
    ushort v2 = h2b[(size_t)s2 * 64 + lane];
    ushort v3 = h2b[(size_t)s3 * 64 + lane];
    ushort v4 = h2b[(size_t)s4 * 64 + lane];
    ushort v5 = h2b[(size_t)s5 * 64 + lane];
    ushort v6 = h2b[(size_t)s6 * 64 + lane];
    ushort v7 = h2b[(size_t)s7 * 64 + lane];
    a += __uint_as_float((uint)v0 << 16) + __uint_as_float((uint)v1 << 16)
       + __uint_as_float((uint)v2 << 16) + __uint_as_float((uint)v3 << 16)
       + __uint_as_float((uint)v4 << 16) + __uint_as_float((uint)v5 << 16)
       + __uint_as_float((uint)v6 << 16) + __uint_as_float((uint)v7 << 16);
  }
  for (; k < kmax; ++k) {
    int s = __shfl(sidx, k, 64);
    a += __uint_as_float((uint)h2b[(size_t)s * 64 + lane] << 16);
  }
  for (int j = b + 64; j < e; ++j)
    a += __uint_as_float((uint)h2b[(size_t)esrc[j] * 64 + lane] << 16);

  out2[(size_t)n * 64 + lane] = fmaf(dinv[n], a, b2[lane]);
}

// logits[e] = dot(z[a],z[b]) over 64 dims -- 16 lanes/edge, float4/lane
__global__ __launch_bounds__(256) void k_decode(const int* __restrict__ ia,
                                                const int* __restrict__ ib,
                                                const float* __restrict__ z,
                                                float* __restrict__ out, int M) {
  const int sub = threadIdx.x & 15;
  int e = (blockIdx.x * 256 + threadIdx.x) >> 4;
  if (e >= M) return;
  int a = ia[e], b = ib[e];
  float4 va = ((const float4*)z)[(size_t)a * 16 + sub];
  float4 vb = ((const float4*)z)[(size_t)b * 16 + sub];
  float v = va.x * vb.x + va.y * vb.y + va.z * vb.z + va.w * vb.w;
  v += __shfl_xor(v, 8, 64);
  v += __shfl_xor(v, 4, 64);
  v += __shfl_xor(v, 2, 64);
  v += __shfl_xor(v, 1, 64);
  if (sub == 0) out[e] = v;
}

extern "C" void kernel_launch(void* const* d_in, const int* in_sizes, int n_in,
                              void* d_out, int out_size, void* d_ws, size_t ws_size,
                              hipStream_t stream) {
  const float* x   = (const float*)d_in[0];
  const int*   ei  = (const int*)d_in[1];
  const int*   eli = (const int*)d_in[2];
  const float* W1  = (const float*)d_in[3];
  const float* b1  = (const float*)d_in[4];
  const float* W2  = (const float*)d_in[5];
  const float* b2  = (const float*)d_in[6];
  float* outp = (float*)d_out;

  const int E = in_sizes[1] / 2;   // 800000
  const int M = in_sizes[2] / 2;   // 200000
  const int* src = ei;
  const int* dst = ei + E;
  const int* la  = eli;
  const int* lb  = eli + M;

  float* ws     = (float*)d_ws;
  float* dinv   = ws;
  int*   rowptr = (int*)(ws + OFF_ROWPTR);
  int*   bsum   = (int*)(ws + OFF_BSUM);
  int*   boff   = (int*)(ws + OFF_BOFF);
  int*   cnt    = (int*)(ws + OFF_CNT);
  int*   esrc   = (int*)(ws + OFF_ESRC);
  int*   epos   = (int*)(ws + OFF_EPOS);
  _Float16* W1t = (_Float16*)(ws + OFF_W1T);
  _Float16* W2t = (_Float16*)(ws + OFF_W2T);
  ushort* h1b   = (ushort*)(ws + OFF_H1B);
  ushort* h2b   = (ushort*)(ws + OFF_H1B);   // reuse (h1b dead after pull1)
  float* out1   = ws + OFF_OUT1;
  float* out2   = ws + OFF_OUT2;

  // CSR build + degree norm + weight prep
  k_zero <<<NB, 256, 0, stream>>>(cnt);
  k_hist <<<(E + 255) / 256, 256, 0, stream>>>(dst, E, cnt, epos);
  k_prep <<<96, 256, 0, stream>>>(W1, W2, W1t, W2t);
  k_scan1<<<NB, 256, 0, stream>>>(cnt, rowptr, bsum);
  k_scan2<<<1, 256, 0, stream>>>(bsum, boff);
  k_scan3<<<NB, 256, 0, stream>>>(rowptr, cnt, dinv, boff, E);
  k_fill <<<(E + 255) / 256, 256, 0, stream>>>(src, dst, epos, E, rowptr, esrc);

  // layer 1
  k_gemm1<<<(N_NODES + 63) / 64, 256, 0, stream>>>(x, W1t, dinv, h1b);
  k_pull1<<<12500, 256, 0, stream>>>(rowptr, esrc, dinv, (const uint*)h1b, b1, out1);

  // layer 2
  k_gemm2<<<(N_NODES + 63) / 64, 256, 0, stream>>>(out1, W2t, dinv, h2b);
  k_pull2<<<12500, 256, 0, stream>>>(rowptr, esrc, dinv, h2b, b2, out2);

  // decode
  k_decode<<<12500, 256, 0, stream>>>(la, lb, out2, outp, M);
}

// Round 7
// 226.484 us; speedup vs baseline: 3.2264x; 1.0363x over previous
//
#include <hip/hip_runtime.h>

#define N_NODES 50000
#define NB ((N_NODES + 255) / 256)   // 196 scan blocks

using half8 = __attribute__((ext_vector_type(8))) _Float16;
using half4 = __attribute__((ext_vector_type(4))) _Float16;
using f32x4 = __attribute__((ext_vector_type(4))) float;

// Workspace layout (4-byte units):
//   dinv   [0,       50000)    float
//   rowptr [50048,  100049)    int (50001)
//   bsum   [100096, 100352)    int
//   boff   [100352, 100608)    int
//   cnt    [100608, 150608)    int (in-degree histogram)
//   esrc   [150656, 950656)    int (src per CSR slot)
//   epos   [950656, 1750656)   int (within-bucket position per edge)
//   W1t    [1750656, +8192)    fp16 [128c][128k] transposed+swizzled
//   W2t    [1758848, +4096)    fp16 [64c][128k]  transposed+swizzled
//   h1b    [1762944, +3200000) bf16 50000x128 (=h1*dinv); reused as h2b 50000x64
//   out1   [4962944, +6400000) float 50000x128
//   z      [11362944,+1600000) fp16 50000x64 (decoder input)
// total = 12,962,944 floats = 51.9 MB

#define OFF_ROWPTR 50048
#define OFF_BSUM   100096
#define OFF_BOFF   100352
#define OFF_CNT    100608
#define OFF_ESRC   150656
#define OFF_EPOS   950656
#define OFF_W1T    1750656
#define OFF_W2T    1758848
#define OFF_H1B    1762944
#define OFF_OUT1   4962944
#define OFF_Z      11362944

__device__ __forceinline__ ushort f2bf(float f) {
  uint u = __float_as_uint(f);
  u += 0x7fffu + ((u >> 16) & 1u);   // RNE
  return (ushort)(u >> 16);
}
__device__ __forceinline__ uint pack2(float a, float b) {
  return (uint)f2bf(a) | ((uint)f2bf(b) << 16);
}
__device__ __forceinline__ float blo(uint u) { return __uint_as_float(u << 16); }
__device__ __forceinline__ float bhi(uint u) { return __uint_as_float(u & 0xffff0000u); }

// ---------------- fused: zero histogram + weight prep ----------------
__global__ __launch_bounds__(256) void k_zero_prep(int* __restrict__ cnt,
                                                   const float* __restrict__ W1,
                                                   const float* __restrict__ W2,
                                                   _Float16* __restrict__ W1t,
                                                   _Float16* __restrict__ W2t) {
  int bid = blockIdx.x;
  if (bid < NB) {
    int i = bid * 256 + threadIdx.x;
    if (i < N_NODES) cnt[i] = 0;
    return;
  }
  int i = (bid - NB) * 256 + threadIdx.x;
  if (i < 16384) {
    int c = i >> 7, k = i & 127;
    W1t[c * 128 + (k ^ ((c & 7) << 3))] = (_Float16)W1[k * 128 + c];
  } else if (i < 24576) {
    int j = i - 16384;
    int c = j >> 7, k = j & 127;
    W2t[c * 128 + (k ^ ((c & 7) << 3))] = (_Float16)W2[k * 64 + c];
  }
}

__global__ __launch_bounds__(256) void k_hist(const int* __restrict__ dst, int E,
                                              int* __restrict__ cnt,
                                              int* __restrict__ epos) {
  int i = blockIdx.x * 256 + threadIdx.x;
  if (i < E) epos[i] = atomicAdd(&cnt[dst[i]], 1);
}

__global__ __launch_bounds__(256) void k_scan1(const int* __restrict__ cnt,
                                               int* __restrict__ rowptr,
                                               int* __restrict__ bsum) {
  __shared__ int tmp[256];
  int i = blockIdx.x * 256 + threadIdx.x;
  int v = (i < N_NODES) ? cnt[i] : 0;
  tmp[threadIdx.x] = v;
  __syncthreads();
  for (int off = 1; off < 256; off <<= 1) {
    int t = (threadIdx.x >= off) ? tmp[threadIdx.x - off] : 0;
    __syncthreads();
    tmp[threadIdx.x] += t;
    __syncthreads();
  }
  if (i < N_NODES) rowptr[i] = tmp[threadIdx.x] - v;
  if (threadIdx.x == 255) bsum[blockIdx.x] = tmp[255];
}

__global__ __launch_bounds__(256) void k_scan2(const int* __restrict__ bsum,
                                               int* __restrict__ boff) {
  __shared__ int tmp[256];
  int v = (threadIdx.x < NB) ? bsum[threadIdx.x] : 0;
  tmp[threadIdx.x] = v;
  __syncthreads();
  for (int off = 1; off < 256; off <<= 1) {
    int t = (threadIdx.x >= off) ? tmp[threadIdx.x - off] : 0;
    __syncthreads();
    tmp[threadIdx.x] += t;
    __syncthreads();
  }
  if (threadIdx.x < NB) boff[threadIdx.x] = tmp[threadIdx.x] - v;
}

__global__ __launch_bounds__(256) void k_scan3(int* __restrict__ rowptr,
                                               const int* __restrict__ cnt,
                                               float* __restrict__ dinv,
                                               const int* __restrict__ boff, int E) {
  int i = blockIdx.x * 256 + threadIdx.x;
  if (i < N_NODES) {
    rowptr[i] += boff[blockIdx.x];
    dinv[i] = rsqrtf(1.0f + (float)cnt[i]);
  }
  if (i == 0) rowptr[N_NODES] = E;
}

__global__ __launch_bounds__(256) void k_fill(const int* __restrict__ src,
                                              const int* __restrict__ dst,
                                              const int* __restrict__ epos, int E,
                                              const int* __restrict__ rowptr,
                                              int* __restrict__ esrc) {
  int e = blockIdx.x * 256 + threadIdx.x;
  if (e < E) esrc[rowptr[dst[e]] + epos[e]] = src[e];
}

// ---------------- layer 1 GEMM (MFMA f16): h1b = bf16((x @ W1) * dinv) -------
__global__ __launch_bounds__(256) void k_gemm1(const float* __restrict__ x,
                                               const _Float16* __restrict__ W1t,
                                               const float* __restrict__ dinv,
                                               ushort* __restrict__ h1b) {
  __shared__ _Float16 Wl[128 * 128];   // 32 KB (pre-swizzled)
  __shared__ _Float16 xs[64 * 128];    // 16 KB (swizzled here)
  const int tid = threadIdx.x;
  const int lane = tid & 63;
  const int wv = tid >> 6;
  const int n0 = blockIdx.x * 64;

  for (int i = tid; i < 128 * 128 / 8; i += 256)
    *(float4*)&Wl[i * 8] = *(const float4*)&W1t[i * 8];
  for (int i = tid; i < 64 * 32; i += 256) {
    int nn = i >> 5, k4 = (i & 31) * 4;
    int gr = min(n0 + nn, N_NODES - 1);
    float4 v = *(const float4*)&x[(size_t)gr * 128 + k4];
    half4 hv;
    hv[0] = (_Float16)v.x; hv[1] = (_Float16)v.y;
    hv[2] = (_Float16)v.z; hv[3] = (_Float16)v.w;
    *(half4*)&xs[nn * 128 + (k4 ^ ((nn & 7) << 3))] = hv;
  }
  __syncthreads();

  f32x4 acc[8];
#pragma unroll
  for (int c = 0; c < 8; ++c) acc[c] = (f32x4){0.f, 0.f, 0.f, 0.f};

  const int m15 = lane & 15;
  const int kc = lane >> 4;
  const int xrow = wv * 16 + m15;

#pragma unroll
  for (int kt = 0; kt < 4; ++kt) {
    int e0 = kt * 32 + kc * 8;
    half8 bfrag = *(half8*)&xs[xrow * 128 + (e0 ^ ((xrow & 7) << 3))];
#pragma unroll
    for (int ct = 0; ct < 8; ++ct) {
      int wrow = ct * 16 + m15;
      half8 afrag = *(half8*)&Wl[wrow * 128 + (e0 ^ ((wrow & 7) << 3))];
      acc[ct] = __builtin_amdgcn_mfma_f32_16x16x32_f16(afrag, bfrag, acc[ct], 0, 0, 0);
    }
  }

  int n = n0 + wv * 16 + m15;
  if (n < N_NODES) {
    float dl = dinv[n];
#pragma unroll
    for (int ct = 0; ct < 8; ++ct) {
      int c = ct * 16 + kc * 4;
      uint2 p;
      p.x = pack2(acc[ct][0] * dl, acc[ct][1] * dl);
      p.y = pack2(acc[ct][2] * dl, acc[ct][3] * dl);
      *(uint2*)&h1b[(size_t)n * 128 + c] = p;
    }
  }
}

// out1[n] = dinv[n]*(h1b[n] + sum_{s} h1b[s]) + b1  -- shfl-broadcast, unroll 16
__global__ __launch_bounds__(256) void k_pull1(const int* __restrict__ rowptr,
                                               const int* __restrict__ esrc,
                                               const float* __restrict__ dinv,
                                               const uint* __restrict__ h1b,
                                               const float* __restrict__ b1,
                                               float* __restrict__ out1) {
  int n = (blockIdx.x * 256 + threadIdx.x) >> 6;
  int lane = threadIdx.x & 63;
  if (n >= N_NODES) return;
  int b = rowptr[n], e = rowptr[n + 1];
  int deg = e - b;

  uint u = h1b[(size_t)n * 64 + lane];   // self-loop
  float a0 = blo(u), a1 = bhi(u);

  int sidx = (lane < deg) ? esrc[b + lane] : 0;
  int kmax = deg < 64 ? deg : 64;
  int k = 0;
  for (; k + 15 < kmax; k += 16) {
    uint uu[16];
#pragma unroll
    for (int q = 0; q < 16; ++q) {
      int s = __shfl(sidx, k + q, 64);
      uu[q] = h1b[(size_t)s * 64 + lane];
    }
#pragma unroll
    for (int q = 0; q < 16; ++q) { a0 += blo(uu[q]); a1 += bhi(uu[q]); }
  }
  for (; k + 7 < kmax; k += 8) {
    uint uu[8];
#pragma unroll
    for (int q = 0; q < 8; ++q) {
      int s = __shfl(sidx, k + q, 64);
      uu[q] = h1b[(size_t)s * 64 + lane];
    }
#pragma unroll
    for (int q = 0; q < 8; ++q) { a0 += blo(uu[q]); a1 += bhi(uu[q]); }
  }
  for (; k < kmax; ++k) {
    int s = __shfl(sidx, k, 64);
    uint uu = h1b[(size_t)s * 64 + lane];
    a0 += blo(uu);
    a1 += bhi(uu);
  }
  for (int j = b + 64; j < e; ++j) {
    uint uu = h1b[(size_t)esrc[j] * 64 + lane];
    a0 += blo(uu);
    a1 += bhi(uu);
  }

  float dd = dinv[n];
  float2 bb = ((const float2*)b1)[lane];
  float2 o;
  o.x = fmaf(dd, a0, bb.x);
  o.y = fmaf(dd, a1, bb.y);
  ((float2*)out1)[(size_t)n * 64 + lane] = o;
}

// ---------------- layer 2 GEMM (MFMA f16): h2b = bf16((relu(out1)@W2)*dinv) --
__global__ __launch_bounds__(256) void k_gemm2(const float* __restrict__ out1,
                                               const _Float16* __restrict__ W2t,
                                               const float* __restrict__ dinv,
                                               ushort* __restrict__ h2b) {
  __shared__ _Float16 Wl[64 * 128];    // 16 KB
  __shared__ _Float16 xs[64 * 128];    // 16 KB
  const int tid = threadIdx.x;
  const int lane = tid & 63;
  const int wv = tid >> 6;
  const int n0 = blockIdx.x * 64;

  for (int i = tid; i < 64 * 128 / 8; i += 256)
    *(float4*)&Wl[i * 8] = *(const float4*)&W2t[i * 8];
  for (int i = tid; i < 64 * 32; i += 256) {
    int nn = i >> 5, k4 = (i & 31) * 4;
    int gr = min(n0 + nn, N_NODES - 1);
    float4 v = *(const float4*)&out1[(size_t)gr * 128 + k4];
    half4 hv;
    hv[0] = (_Float16)fmaxf(v.x, 0.f); hv[1] = (_Float16)fmaxf(v.y, 0.f);
    hv[2] = (_Float16)fmaxf(v.z, 0.f); hv[3] = (_Float16)fmaxf(v.w, 0.f);
    *(half4*)&xs[nn * 128 + (k4 ^ ((nn & 7) << 3))] = hv;
  }
  __syncthreads();

  f32x4 acc[4];
#pragma unroll
  for (int c = 0; c < 4; ++c) acc[c] = (f32x4){0.f, 0.f, 0.f, 0.f};

  const int m15 = lane & 15;
  const int kc = lane >> 4;
  const int xrow = wv * 16 + m15;

#pragma unroll
  for (int kt = 0; kt < 4; ++kt) {
    int e0 = kt * 32 + kc * 8;
    half8 bfrag = *(half8*)&xs[xrow * 128 + (e0 ^ ((xrow & 7) << 3))];
#pragma unroll
    for (int ct = 0; ct < 4; ++ct) {
      int wrow = ct * 16 + m15;
      half8 afrag = *(half8*)&Wl[wrow * 128 + (e0 ^ ((wrow & 7) << 3))];
      acc[ct] = __builtin_amdgcn_mfma_f32_16x16x32_f16(afrag, bfrag, acc[ct], 0, 0, 0);
    }
  }

  int n = n0 + wv * 16 + m15;
  if (n < N_NODES) {
    float dl = dinv[n];
#pragma unroll
    for (int ct = 0; ct < 4; ++ct) {
      int c = ct * 16 + kc * 4;
      uint2 p;
      p.x = pack2(acc[ct][0] * dl, acc[ct][1] * dl);
      p.y = pack2(acc[ct][2] * dl, acc[ct][3] * dl);
      *(uint2*)&h2b[(size_t)n * 64 + c] = p;
    }
  }
}

// z[n] = fp16(dinv[n]*(h2b[n] + sum h2b[s]) + b2)  -- shfl-broadcast, unroll 16
__global__ __launch_bounds__(256) void k_pull2(const int* __restrict__ rowptr,
                                               const int* __restrict__ esrc,
                                               const float* __restrict__ dinv,
                                               const ushort* __restrict__ h2b,
                                               const float* __restrict__ b2,
                                               _Float16* __restrict__ z) {
  int n = (blockIdx.x * 256 + threadIdx.x) >> 6;
  int lane = threadIdx.x & 63;
  if (n >= N_NODES) return;
  int b = rowptr[n], e = rowptr[n + 1];
  int deg = e - b;

  float a = __uint_as_float((uint)h2b[(size_t)n * 64 + lane] << 16);  // self

  int sidx = (lane < deg) ? esrc[b + lane] : 0;
  int kmax = deg < 64 ? deg : 64;
  int k = 0;
  for (; k + 15 < kmax; k += 16) {
    ushort vv[16];
#pragma unroll
    for (int q = 0; q < 16; ++q) {
      int s = __shfl(sidx, k + q, 64);
      vv[q] = h2b[(size_t)s * 64 + lane];
    }
#pragma unroll
    for (int q = 0; q < 16; ++q) a += __uint_as_float((uint)vv[q] << 16);
  }
  for (; k + 7 < kmax; k += 8) {
    ushort vv[8];
#pragma unroll
    for (int q = 0; q < 8; ++q) {
      int s = __shfl(sidx, k + q, 64);
      vv[q] = h2b[(size_t)s * 64 + lane];
    }
#pragma unroll
    for (int q = 0; q < 8; ++q) a += __uint_as_float((uint)vv[q] << 16);
  }
  for (; k < kmax; ++k) {
    int s = __shfl(sidx, k, 64);
    a += __uint_as_float((uint)h2b[(size_t)s * 64 + lane] << 16);
  }
  for (int j = b + 64; j < e; ++j)
    a += __uint_as_float((uint)h2b[(size_t)esrc[j] * 64 + lane] << 16);

  z[(size_t)n * 64 + lane] = (_Float16)fmaf(dinv[n], a, b2[lane]);
}

// logits[e] = dot(z[a],z[b]) over 64 dims -- 8 lanes/edge, half8/lane
__global__ __launch_bounds__(256) void k_decode(const int* __restrict__ ia,
                                                const int* __restrict__ ib,
                                                const _Float16* __restrict__ z,
                                                float* __restrict__ out, int M) {
  const int sub = threadIdx.x & 7;
  int e = (blockIdx.x * 256 + threadIdx.x) >> 3;
  if (e >= M) return;
  int a = ia[e], b = ib[e];
  half8 va = ((const half8*)z)[(size_t)a * 8 + sub];
  half8 vb = ((const half8*)z)[(size_t)b * 8 + sub];
  float v = 0.f;
#pragma unroll
  for (int i = 0; i < 8; ++i) v += (float)va[i] * (float)vb[i];
  v += __shfl_xor(v, 4, 64);
  v += __shfl_xor(v, 2, 64);
  v += __shfl_xor(v, 1, 64);
  if (sub == 0) out[e] = v;
}

extern "C" void kernel_launch(void* const* d_in, const int* in_sizes, int n_in,
                              void* d_out, int out_size, void* d_ws, size_t ws_size,
                              hipStream_t stream) {
  const float* x   = (const float*)d_in[0];
  const int*   ei  = (const int*)d_in[1];
  const int*   eli = (const int*)d_in[2];
  const float* W1  = (const float*)d_in[3];
  const float* b1  = (const float*)d_in[4];
  const float* W2  = (const float*)d_in[5];
  const float* b2  = (const float*)d_in[6];
  float* outp = (float*)d_out;

  const int E = in_sizes[1] / 2;   // 800000
  const int M = in_sizes[2] / 2;   // 200000
  const int* src = ei;
  const int* dst = ei + E;
  const int* la  = eli;
  const int* lb  = eli + M;

  float* ws     = (float*)d_ws;
  float* dinv   = ws;
  int*   rowptr = (int*)(ws + OFF_ROWPTR);
  int*   bsum   = (int*)(ws + OFF_BSUM);
  int*   boff   = (int*)(ws + OFF_BOFF);
  int*   cnt    = (int*)(ws + OFF_CNT);
  int*   esrc   = (int*)(ws + OFF_ESRC);
  int*   epos   = (int*)(ws + OFF_EPOS);
  _Float16* W1t = (_Float16*)(ws + OFF_W1T);
  _Float16* W2t = (_Float16*)(ws + OFF_W2T);
  ushort* h1b   = (ushort*)(ws + OFF_H1B);
  ushort* h2b   = (ushort*)(ws + OFF_H1B);   // reuse (h1b dead after pull1)
  float* out1   = ws + OFF_OUT1;
  _Float16* z   = (_Float16*)(ws + OFF_Z);

  // CSR build + degree norm + weight prep
  k_zero_prep<<<NB + 96, 256, 0, stream>>>(cnt, W1, W2, W1t, W2t);
  k_hist <<<(E + 255) / 256, 256, 0, stream>>>(dst, E, cnt, epos);
  k_scan1<<<NB, 256, 0, stream>>>(cnt, rowptr, bsum);
  k_scan2<<<1, 256, 0, stream>>>(bsum, boff);
  k_scan3<<<NB, 256, 0, stream>>>(rowptr, cnt, dinv, boff, E);
  k_fill <<<(E + 255) / 256, 256, 0, stream>>>(src, dst, epos, E, rowptr, esrc);

  // layer 1
  k_gemm1<<<(N_NODES + 63) / 64, 256, 0, stream>>>(x, W1t, dinv, h1b);
  k_pull1<<<12500, 256, 0, stream>>>(rowptr, esrc, dinv, (const uint*)h1b, b1, out1);

  // layer 2
  k_gemm2<<<(N_NODES + 63) / 64, 256, 0, stream>>>(out1, W2t, dinv, h2b);
  k_pull2<<<12500, 256, 0, stream>>>(rowptr, esrc, dinv, h2b, b2, z);

  // decode
  k_decode<<<6250, 256, 0, stream>>>(la, lb, z, outp, M);
}